// Round 12
// baseline (386.315 us; speedup 1.0000x reference)
//
#include <hip/hip_runtime.h>
#include <hip/hip_bf16.h>

typedef float f32x4 __attribute__((ext_vector_type(4)));
typedef __bf16 bfv8 __attribute__((ext_vector_type(8)));

constexpr int Bc = 4, Sc = 2048, Ec = 1024, Hc = 16, Dc = 64;
constexpr int Mc = Bc * Sc;  // 8192 rows

__device__ __forceinline__ uint pkbf(float lo, float hi) {
  uint r;
  asm("v_cvt_pk_bf16_f32 %0, %1, %2" : "=v"(r) : "v"(lo), "v"(hi));
  return r;
}
__device__ __forceinline__ ushort f2bf(float f) {
  __hip_bfloat16 h = __float2bfloat16(f);
  return __builtin_bit_cast(ushort, h);
}

typedef __attribute__((address_space(1))) unsigned int as1_u32;
typedef __attribute__((address_space(3))) unsigned int as3_u32;
__device__ __forceinline__ void cp16(const ushort* g, ushort* l) {
  // async global->LDS, 16B per lane; LDS dest = wave-uniform base + lane*16
  __builtin_amdgcn_global_load_lds((as1_u32*)g, (as3_u32*)l, 16, 0, 0);
}

// ---------------- weight convert + transpose: W[K][N] f32 -> WT[N][K] bf16 ----
__global__ __launch_bounds__(256) void wcvt_kernel(const float* __restrict__ W,
                                                   ushort* __restrict__ WT,
                                                   int K, int N) {
  __shared__ float t[32][33];
  int k0 = blockIdx.x * 32, n0 = blockIdx.y * 32;
  int tx = threadIdx.x, ty = threadIdx.y;  // (32,8)
#pragma unroll
  for (int i = 0; i < 32; i += 8)
    t[ty + i][tx] = W[(size_t)(k0 + ty + i) * N + n0 + tx];
  __syncthreads();
#pragma unroll
  for (int i = 0; i < 32; i += 8)
    WT[(size_t)(n0 + ty + i) * K + k0 + tx] = f2bf(t[tx][ty + i]);
}

// ---------------- LayerNorm: row of 1024, one block per row ------------------
__global__ __launch_bounds__(256) void ln_kernel(const float* in,
                                                 const float* __restrict__ g,
                                                 const float* __restrict__ bb,
                                                 float* of, ushort* ob) {
  int row = blockIdx.x;
  int t = threadIdx.x;
  float4 x = reinterpret_cast<const float4*>(in + (size_t)row * Ec)[t];
  float s = x.x + x.y + x.z + x.w;
  float q = x.x * x.x + x.y * x.y + x.z * x.z + x.w * x.w;
#pragma unroll
  for (int o = 32; o > 0; o >>= 1) {
    s += __shfl_down(s, o);
    q += __shfl_down(q, o);
  }
  __shared__ float red[10];
  int wv = t >> 6;
  if ((t & 63) == 0) { red[wv] = s; red[4 + wv] = q; }
  __syncthreads();
  if (t == 0) {
    float S = red[0] + red[1] + red[2] + red[3];
    float Q = red[4] + red[5] + red[6] + red[7];
    float mu = S * (1.f / Ec);
    float var = Q * (1.f / Ec) - mu * mu;
    red[8] = mu;
    red[9] = rsqrtf(var + 1e-5f);
  }
  __syncthreads();
  float mu = red[8], rs = red[9];
  float4 gg = reinterpret_cast<const float4*>(g)[t];
  float4 b4 = reinterpret_cast<const float4*>(bb)[t];
  float4 y;
  y.x = (x.x - mu) * rs * gg.x + b4.x;
  y.y = (x.y - mu) * rs * gg.y + b4.y;
  y.z = (x.z - mu) * rs * gg.z + b4.z;
  y.w = (x.w - mu) * rs * gg.w + b4.w;
  reinterpret_cast<float4*>(of + (size_t)row * Ec)[t] = y;
  uint2 u;
  u.x = pkbf(y.x, y.y);
  u.y = pkbf(y.z, y.w);
  reinterpret_cast<uint2*>(ob + (size_t)row * Ec)[t] = u;
}

// ======== 256x256 8-wave 4-phase GEMM (QKV / W1) ========
// BK=64, 512 threads, LDS 128KiB double-buffered, counted vmcnt(8) + raw
// barriers; per-K-tile compute split into 4 phases (ksub x M-half), each
// {ds_read frags; setprio(1); 16 MFMA; setprio(0); barrier} -> wave role-split.
// Swizzle: chunk ^ (row&7) on both stage-source and frag-read (involution).
// MODE 0: fused QKV epilogue; MODE 2: bf16 gelu(acc+bias).
template <int MODE>
__global__ __launch_bounds__(512, 2) void gemm256_kernel(
    int M, int N, int K, const ushort* __restrict__ A,
    const ushort* __restrict__ BT, const float* __restrict__ b0,
    const float* __restrict__ b1, const float* __restrict__ b2,
    ushort* o0, ushort* o1, ushort* o2, float qscale) {
  __shared__ __align__(16) ushort As[2][256 * 64];
  __shared__ __align__(16) ushort Bs[2][256 * 64];
  const int tid = threadIdx.x;
  const int lane = tid & 63, wave = tid >> 6;  // 8 waves
  const int wr = wave >> 2, wc = wave & 3;     // 2 x 4
  const int fr = lane & 15, fq = lane >> 4;
  const int nx = gridDim.x;
  int flat = blockIdx.x + nx * blockIdx.y;
  int cpx = (nx * gridDim.y) >> 3;  // nwg % 8 == 0 for both launches
  int work = (flat & 7) * cpx + (flat >> 3);
  const int n0 = (work % nx) * 256, m0 = (work / nx) * 256;

  f32x4 acc[8][4];
#pragma unroll
  for (int i = 0; i < 8; i++)
#pragma unroll
    for (int j = 0; j < 4; j++) acc[i][j] = f32x4{0.f, 0.f, 0.f, 0.f};

  const int srow = tid >> 3;  // 0..63
  const int sslot = tid & 7;

  auto STAGE = [&](int p, int k0) {
#pragma unroll
    for (int c = 0; c < 4; ++c) {
      int row = c * 64 + srow;
      int scol = (sslot ^ (row & 7)) * 8;  // inverse-swizzled source
      cp16(A + (size_t)(m0 + row) * K + k0 + scol,
           &As[p][(c * 64 + wave * 8) * 64]);
      cp16(BT + (size_t)(n0 + row) * K + k0 + scol,
           &Bs[p][(c * 64 + wave * 8) * 64]);
    }
  };

  STAGE(0, 0);
  const int nt = K >> 6;
  for (int kt = 0; kt < nt; ++kt) {
    const int p = kt & 1;
    if (kt + 1 < nt) {
      STAGE(p ^ 1, (kt + 1) << 6);
      asm volatile("s_waitcnt vmcnt(8)" ::: "memory");  // tile kt landed
    } else {
      asm volatile("s_waitcnt vmcnt(0)" ::: "memory");
    }
    __builtin_amdgcn_s_barrier();
#pragma unroll
    for (int kk = 0; kk < 2; ++kk) {
      bfv8 bfr[4];
#pragma unroll
      for (int n = 0; n < 4; ++n) {
        int row = wc * 64 + n * 16 + fr;
        bfr[n] = *reinterpret_cast<const bfv8*>(
            &Bs[p][row * 64 + (((kk * 4 + fq) ^ (row & 7)) * 8)]);
      }
#pragma unroll
      for (int mh = 0; mh < 2; ++mh) {
        bfv8 af[4];
#pragma unroll
        for (int mm = 0; mm < 4; ++mm) {
          int row = wr * 128 + (mh * 4 + mm) * 16 + fr;
          af[mm] = *reinterpret_cast<const bfv8*>(
              &As[p][row * 64 + (((kk * 4 + fq) ^ (row & 7)) * 8)]);
        }
        __builtin_amdgcn_s_setprio(1);
#pragma unroll
        for (int mm = 0; mm < 4; ++mm)
#pragma unroll
          for (int n = 0; n < 4; ++n)
            acc[mh * 4 + mm][n] = __builtin_amdgcn_mfma_f32_16x16x32_bf16(
                af[mm], bfr[n], acc[mh * 4 + mm][n], 0, 0, 0);
        __builtin_amdgcn_s_setprio(0);
        if (!(kk == 1 && mh == 1)) __builtin_amdgcn_s_barrier();  // phase edge
      }
    }
    __builtin_amdgcn_sched_barrier(0);
    __builtin_amdgcn_s_barrier();  // tile edge: all reads of buf p done
  }

#pragma unroll
  for (int m = 0; m < 8; m++) {
#pragma unroll
    for (int n = 0; n < 4; n++) {
      const int row0 = m0 + wr * 128 + m * 16 + fq * 4;
      const int col = n0 + wc * 64 + n * 16 + fr;
      if constexpr (MODE == 0) {
        const int region = col >> 10, c1 = col & (Ec - 1);
        const int b = row0 >> 11, s0 = row0 & (Sc - 1);
        const int h = c1 >> 6, d = c1 & (Dc - 1);
        const float bb = (region == 0 ? b0 : region == 1 ? b1 : b2)[c1];
        if (region == 2) {
          uint2 u;
          u.x = pkbf(acc[m][n][0] + bb, acc[m][n][1] + bb);
          u.y = pkbf(acc[m][n][2] + bb, acc[m][n][3] + bb);
          *reinterpret_cast<uint2*>(
              &o2[(((size_t)b * Hc + h) * Dc + d) * Sc + s0]) = u;
        } else {
          ushort* dst = region ? o1 : o0;
          const float sc = region ? 1.f : qscale;
#pragma unroll
          for (int r = 0; r < 4; r++)
            dst[(((size_t)b * Hc + h) * Sc + s0 + r) * Dc + d] =
                f2bf((acc[m][n][r] + bb) * sc);
        }
      } else {
        const float bb = b0[col];
#pragma unroll
        for (int r = 0; r < 4; r++) {
          float vacc = acc[m][n][r] + bb;
          vacc = 0.5f * vacc * (1.f + erff(vacc * 0.70710678118f));
          o0[(size_t)(row0 + r) * N + col] = f2bf(vacc);
        }
      }
    }
  }
}

// ---------------- GEMM 128x128 (Wo / W2): BK=64, dbuf, counted vmcnt(8) -----
// MODE 1: f32 out = acc + bias + resid (row-major)
template <int MODE>
__global__ __launch_bounds__(256, 2) void gemm_kernel(
    int M, int N, int K, const ushort* __restrict__ A,
    const ushort* __restrict__ BT, const float* __restrict__ b0,
    const float* resid, float* outF, float qscale) {
  __shared__ __align__(16) ushort As[2][128 * 64];
  __shared__ __align__(16) ushort Bs[2][128 * 64];
  const int tid = threadIdx.x;
  const int lane = tid & 63, wave = tid >> 6;
  const int wr = wave >> 1, wc = wave & 1;
  const int fr = lane & 15, fq = lane >> 4;
  const int nx = gridDim.x;
  int flat = blockIdx.x + nx * blockIdx.y;
  int cpx = (nx * gridDim.y) >> 3;
  int work = (flat & 7) * cpx + (flat >> 3);
  const int n0 = (work % nx) * 128, m0 = (work / nx) * 128;

  f32x4 acc[4][4];
#pragma unroll
  for (int i = 0; i < 4; i++)
#pragma unroll
    for (int j = 0; j < 4; j++) acc[i][j] = f32x4{0.f, 0.f, 0.f, 0.f};

  const int srow = tid >> 3;   // 0..31 (+32 per chunk)
  const int sslot = tid & 7;   // 16B slot within 128B row

  auto STAGE = [&](int p, int k0) {
#pragma unroll
    for (int c = 0; c < 4; ++c) {
      int row = c * 32 + srow;
      int scol = (sslot ^ (2 * (row & 3))) * 8;  // inverse-swizzled source
      cp16(A + (size_t)(m0 + row) * K + k0 + scol,
           &As[p][(c * 256 + wave * 64) * 8]);
      cp16(BT + (size_t)(n0 + row) * K + k0 + scol,
           &Bs[p][(c * 256 + wave * 64) * 8]);
    }
  };

  STAGE(0, 0);
  const int nt = K >> 6;
  for (int kt = 0; kt < nt; ++kt) {
    const int p = kt & 1;
    if (kt + 1 < nt) {
      STAGE(p ^ 1, (kt + 1) << 6);
      asm volatile("s_waitcnt vmcnt(8)" ::: "memory");  // tile kt landed
    } else {
      asm volatile("s_waitcnt vmcnt(0)" ::: "memory");
    }
    __builtin_amdgcn_s_barrier();
#pragma unroll
    for (int kk = 0; kk < 2; ++kk) {
      bfv8 af[4], bf[4];
#pragma unroll
      for (int m = 0; m < 4; m++) {
        int row = wr * 64 + m * 16 + fr;
        af[m] = *reinterpret_cast<const bfv8*>(
            &As[p][row * 64 + ((kk * 32 + fq * 8) ^ ((fr & 3) << 4))]);
      }
#pragma unroll
      for (int n = 0; n < 4; n++) {
        int row = wc * 64 + n * 16 + fr;
        bf[n] = *reinterpret_cast<const bfv8*>(
            &Bs[p][row * 64 + ((kk * 32 + fq * 8) ^ ((fr & 3) << 4))]);
      }
      __builtin_amdgcn_s_setprio(1);
#pragma unroll
      for (int m = 0; m < 4; m++)
#pragma unroll
        for (int n = 0; n < 4; n++)
          acc[m][n] =
              __builtin_amdgcn_mfma_f32_16x16x32_bf16(af[m], bf[n], acc[m][n], 0, 0, 0);
      __builtin_amdgcn_s_setprio(0);
    }
    __builtin_amdgcn_sched_barrier(0);
    __builtin_amdgcn_s_barrier();
  }

#pragma unroll
  for (int m = 0; m < 4; m++) {
#pragma unroll
    for (int n = 0; n < 4; n++) {
      const int row0 = m0 + wr * 64 + m * 16 + fq * 4;
      const int col = n0 + wc * 64 + n * 16 + fr;
      const float bb = b0[col];
#pragma unroll
      for (int r = 0; r < 4; r++) {
        int row = row0 + r;
        size_t idx = (size_t)row * N + col;
        outF[idx] = acc[m][n][r] + bb + resid[idx];
      }
    }
  }
}

// ---------------- Flash attention (32 q-rows per wave, 128 per block) --------
// (unchanged from R11)
__global__ __launch_bounds__(256) void attn_kernel(const ushort* __restrict__ q,
                                                   const ushort* __restrict__ k,
                                                   const ushort* __restrict__ vt,
                                                   ushort* __restrict__ o) {
  int flat = blockIdx.x;                     // 1024 blocks
  int swz = (flat & 7) * 128 + (flat >> 3);  // XCD-chunked: 8 heads per XCD
  const int qb = swz & 15;                   // 16 q-blocks of 128 rows
  const int bh = swz >> 4;
  const int tid = threadIdx.x, lane = tid & 63, wave = tid >> 6;
  const int fr = lane & 15, fq = lane >> 4;
  const size_t base = (size_t)bh * Sc * Dc;
  const int q0 = qb * 128 + wave * 32;

  __shared__ __align__(16) ushort Ks[2][64 * 64];  // [key][d], XOR-swizzled
  __shared__ __align__(16) ushort Vt[2][64 * 64];  // [d][key], XOR-swizzled
  __shared__ __align__(16) ushort Ps[4][16 * 64];  // per-wave P, XOR-swizzled

  bfv8 qf0[2], qf1[2];
#pragma unroll
  for (int f = 0; f < 2; ++f) {
    const ushort* qp = q + base + (size_t)(q0 + f * 16 + fr) * Dc + fq * 8;
    qf0[f] = *reinterpret_cast<const bfv8*>(qp);
    qf1[f] = *reinterpret_cast<const bfv8*>(qp + 32);
  }

  const bfv8 ones = __builtin_bit_cast(bfv8, uint4{0x3F803F80u, 0x3F803F80u,
                                                  0x3F803F80u, 0x3F803F80u});

  f32x4 oacc[2][4];  // [frag][dtile]
  f32x4 oaccL[2];    // row-sum accumulator (l)
#pragma unroll
  for (int f = 0; f < 2; ++f) {
    oaccL[f] = f32x4{0.f, 0.f, 0.f, 0.f};
#pragma unroll
    for (int d = 0; d < 4; ++d) oacc[f][d] = f32x4{0.f, 0.f, 0.f, 0.f};
  }
  float mrow[2] = {-3e38f, -3e38f};

  const int r8 = tid >> 3;  // staging row 0..31
  const int c8 = tid & 7;   // staging 16B chunk

  auto STAGE = [&](int p, int key0) {
#pragma unroll
    for (int i = 0; i < 2; ++i) {
      int row = i * 32 + r8;
      int sc = (c8 ^ (row & 7)) * 8;  // inverse-swizzled source
      cp16(k + base + (size_t)(key0 + row) * Dc + sc,
           &Ks[p][i * 2048 + wave * 512]);
      cp16(vt + base + (size_t)row * Sc + key0 + sc,
           &Vt[p][i * 2048 + wave * 512]);
    }
  };

  const int sA = (fq ^ (fr & 7)) * 8;
  const int sB = ((fq + 4) ^ (fr & 7)) * 8;

  const int pswz = 2 * (fr & 7);
  const int pr0 = fr * 64 + ((fq * 2) ^ pswz) * 4;
  const int pr1 = fr * 64 + ((fq * 2 + 8) ^ pswz) * 4;

  STAGE(0, 0);
  constexpr int NT = Sc / 64;
  for (int kt = 0; kt < NT; ++kt) {
    const int p = kt & 1;
    if (kt + 1 < NT) {
      STAGE(p ^ 1, (kt + 1) * 64);
      asm volatile("s_waitcnt vmcnt(4)" ::: "memory");
    } else {
      asm volatile("s_waitcnt vmcnt(0)" ::: "memory");
    }
    __builtin_amdgcn_s_barrier();

    bfv8 kf0[4], kf1[4], vf0[4], vf1[4];
#pragma unroll
    for (int t = 0; t < 4; ++t) {
      int e = (t * 16 + fr) * 64;
      kf0[t] = *reinterpret_cast<const bfv8*>(&Ks[p][e + sA]);
      kf1[t] = *reinterpret_cast<const bfv8*>(&Ks[p][e + sB]);
      vf0[t] = *reinterpret_cast<const bfv8*>(&Vt[p][e + sA]);
      vf1[t] = *reinterpret_cast<const bfv8*>(&Vt[p][e + sB]);
    }

#pragma unroll
    for (int f = 0; f < 2; ++f) {
      f32x4 sf[4];
      __builtin_amdgcn_s_setprio(1);
#pragma unroll
      for (int t = 0; t < 4; ++t) {
        sf[t] = f32x4{0.f, 0.f, 0.f, 0.f};
        sf[t] = __builtin_amdgcn_mfma_f32_16x16x32_bf16(kf0[t], qf0[f], sf[t], 0, 0, 0);
        sf[t] = __builtin_amdgcn_mfma_f32_16x16x32_bf16(kf1[t], qf1[f], sf[t], 0, 0, 0);
      }
      __builtin_amdgcn_s_setprio(0);
      float mt0 = fmaxf(fmaxf(sf[0][0], sf[0][1]), fmaxf(sf[0][2], sf[0][3]));
      float mt1 = fmaxf(fmaxf(sf[1][0], sf[1][1]), fmaxf(sf[1][2], sf[1][3]));
      float mt2 = fmaxf(fmaxf(sf[2][0], sf[2][1]), fmaxf(sf[2][2], sf[2][3]));
      float mt3 = fmaxf(fmaxf(sf[3][0], sf[3][1]), fmaxf(sf[3][2], sf[3][3]));
      float pmax = fmaxf(fmaxf(mt0, mt1), fmaxf(mt2, mt3));
      float m = mrow[f];
      float mnew = m;
      if (!__all(pmax <= m + 8.f)) {
        float mt = fmaxf(pmax, __shfl_xor(pmax, 16));
        mt = fmaxf(mt, __shfl_xor(mt, 32));
        mnew = fmaxf(m, mt);
        float alpha = __builtin_amdgcn_exp2f(m - mnew);
        float ar[4];
#pragma unroll
        for (int r = 0; r < 4; ++r) ar[r] = __shfl(alpha, fq * 4 + r);
#pragma unroll
        for (int d = 0; d < 4; ++d)
#pragma unroll
          for (int r = 0; r < 4; ++r) oacc[f][d][r] *= ar[r];
#pragma unroll
        for (int r = 0; r < 4; ++r) oaccL[f][r] *= ar[r];
        mrow[f] = mnew;
      }
      ushort* pw = &Ps[wave][0];
#pragma unroll
      for (int t = 0; t < 4; ++t) {
        uint2 pu;
        pu.x = pkbf(__builtin_amdgcn_exp2f(sf[t][0] - mnew),
                    __builtin_amdgcn_exp2f(sf[t][1] - mnew));
        pu.y = pkbf(__builtin_amdgcn_exp2f(sf[t][2] - mnew),
                    __builtin_amdgcn_exp2f(sf[t][3] - mnew));
        int us = fr * 64 + ((t * 4 + fq) ^ pswz) * 4;
        *reinterpret_cast<uint2*>(&pw[us]) = pu;
      }
      bfv8 pf0 = *reinterpret_cast<const bfv8*>(&pw[pr0]);
      bfv8 pf1 = *reinterpret_cast<const bfv8*>(&pw[pr1]);
      __builtin_amdgcn_s_setprio(1);
#pragma unroll
      for (int d = 0; d < 4; ++d) {
        oacc[f][d] = __builtin_amdgcn_mfma_f32_16x16x32_bf16(pf0, vf0[d], oacc[f][d], 0, 0, 0);
        oacc[f][d] = __builtin_amdgcn_mfma_f32_16x16x32_bf16(pf1, vf1[d], oacc[f][d], 0, 0, 0);
      }
      oaccL[f] = __builtin_amdgcn_mfma_f32_16x16x32_bf16(pf0, ones, oaccL[f], 0, 0, 0);
      oaccL[f] = __builtin_amdgcn_mfma_f32_16x16x32_bf16(pf1, ones, oaccL[f], 0, 0, 0);
      __builtin_amdgcn_s_setprio(0);
    }
    __builtin_amdgcn_sched_barrier(0);
    __builtin_amdgcn_s_barrier();
  }

  const int b = bh >> 4, h = bh & 15;
#pragma unroll
  for (int f = 0; f < 2; ++f) {
    float linv[4];
#pragma unroll
    for (int r = 0; r < 4; ++r) linv[r] = 1.f / oaccL[f][r];
#pragma unroll
    for (int d = 0; d < 4; ++d)
#pragma unroll
      for (int r = 0; r < 4; ++r) {
        int sIdx = q0 + f * 16 + fq * 4 + r;
        o[((size_t)(b * Sc + sIdx)) * Ec + h * 64 + d * 16 + fr] =
            f2bf(oacc[f][d][r] * linv[r]);
      }
  }
}

// -----------------------------------------------------------------------------
extern "C" void kernel_launch(void* const* d_in, const int* in_sizes, int n_in,
                              void* d_out, int out_size, void* d_ws, size_t ws_size,
                              hipStream_t stream) {
  const float* inp = (const float*)d_in[0];
  const float* ln1g = (const float*)d_in[1];
  const float* ln1b = (const float*)d_in[2];
  const float* Wq = (const float*)d_in[3];
  const float* bq = (const float*)d_in[4];
  const float* Wk = (const float*)d_in[5];
  const float* bk = (const float*)d_in[6];
  const float* Wv = (const float*)d_in[7];
  const float* bv = (const float*)d_in[8];
  const float* Wo = (const float*)d_in[9];
  const float* bo = (const float*)d_in[10];
  const float* ln2g = (const float*)d_in[11];
  const float* ln2b = (const float*)d_in[12];
  const float* W1 = (const float*)d_in[13];
  const float* b1 = (const float*)d_in[14];
  const float* W2 = (const float*)d_in[15];
  const float* b2 = (const float*)d_in[16];

  char* wsb = (char*)d_ws;
  size_t off = 0;
  auto alloc = [&](size_t bytes) {
    char* p = wsb + off;
    off += (bytes + 255) & ~(size_t)255;
    return p;
  };
  float* xf = (float*)alloc((size_t)Mc * Ec * 4);
  ushort* xb = (ushort*)alloc((size_t)Mc * Ec * 2);
  ushort* qbuf = (ushort*)alloc((size_t)Mc * Ec * 2);
  ushort* kbuf = (ushort*)alloc((size_t)Mc * Ec * 2);
  ushort* vtbuf = (ushort*)alloc((size_t)Mc * Ec * 2);
  ushort* abuf = (ushort*)alloc((size_t)Mc * Ec * 2);
  ushort* h1 = (ushort*)alloc((size_t)Mc * 2 * Ec * 2);
  ushort* WqkvT = (ushort*)alloc((size_t)3 * Ec * Ec * 2);  // [3E][E]
  ushort* WoT = (ushort*)alloc((size_t)Ec * Ec * 2);
  ushort* W1T = (ushort*)alloc((size_t)Ec * 2 * Ec * 2);
  ushort* W2T = (ushort*)alloc((size_t)Ec * 2 * Ec * 2);
  (void)in_sizes; (void)n_in; (void)out_size; (void)ws_size;

  dim3 tb(32, 8);
  wcvt_kernel<<<dim3(Ec / 32, Ec / 32), tb, 0, stream>>>(Wq, WqkvT, Ec, Ec);
  wcvt_kernel<<<dim3(Ec / 32, Ec / 32), tb, 0, stream>>>(Wk, WqkvT + (size_t)Ec * Ec, Ec, Ec);
  wcvt_kernel<<<dim3(Ec / 32, Ec / 32), tb, 0, stream>>>(Wv, WqkvT + (size_t)2 * Ec * Ec, Ec, Ec);
  wcvt_kernel<<<dim3(Ec / 32, Ec / 32), tb, 0, stream>>>(Wo, WoT, Ec, Ec);
  wcvt_kernel<<<dim3(Ec / 32, 2 * Ec / 32), tb, 0, stream>>>(W1, W1T, Ec, 2 * Ec);
  wcvt_kernel<<<dim3(2 * Ec / 32, Ec / 32), tb, 0, stream>>>(W2, W2T, 2 * Ec, Ec);

  ln_kernel<<<Mc, 256, 0, stream>>>(inp, ln1g, ln1b, xf, xb);

  // Fused QKV: 256² 8-wave kernel, N=3072, grid 12x32=384 blocks
  gemm256_kernel<0><<<dim3(3 * Ec / 256, Mc / 256), 512, 0, stream>>>(
      Mc, 3 * Ec, Ec, xb, WqkvT, bq, bk, bv, qbuf, kbuf, vtbuf, 0.18033688f);

  attn_kernel<<<Bc * Hc * (Sc / 128), 256, 0, stream>>>(qbuf, kbuf, vtbuf, abuf);

  gemm_kernel<1><<<dim3(Ec / 128, Mc / 128), 256, 0, stream>>>(
      Mc, Ec, Ec, abuf, WoT, bo, xf, xf, 1.f);

  ln_kernel<<<Mc, 256, 0, stream>>>(xf, ln2g, ln2b, xf, xb);

  // W1 + GELU: 256² kernel, N=2048, grid 8x32=256 blocks (1/CU)
  gemm256_kernel<2><<<dim3(2 * Ec / 256, Mc / 256), 512, 0, stream>>>(
      Mc, 2 * Ec, Ec, xb, W1T, b1, nullptr, nullptr, h1, nullptr, nullptr, 1.f);

  gemm_kernel<1><<<dim3(Ec / 128, Mc / 128), 256, 0, stream>>>(
      Mc, Ec, 2 * Ec, h1, W2T, b2, xf, (float*)d_out, 1.f);
}

// Round 13
// 374.791 us; speedup vs baseline: 1.0307x; 1.0307x over previous
//
#include <hip/hip_runtime.h>
#include <hip/hip_bf16.h>

typedef float f32x4 __attribute__((ext_vector_type(4)));
typedef __bf16 bfv8 __attribute__((ext_vector_type(8)));

constexpr int Bc = 4, Sc = 2048, Ec = 1024, Hc = 16, Dc = 64;
constexpr int Mc = Bc * Sc;  // 8192 rows

__device__ __forceinline__ uint pkbf(float lo, float hi) {
  uint r;
  asm("v_cvt_pk_bf16_f32 %0, %1, %2" : "=v"(r) : "v"(lo), "v"(hi));
  return r;
}
__device__ __forceinline__ ushort f2bf(float f) {
  __hip_bfloat16 h = __float2bfloat16(f);
  return __builtin_bit_cast(ushort, h);
}

typedef __attribute__((address_space(1))) unsigned int as1_u32;
typedef __attribute__((address_space(3))) unsigned int as3_u32;
__device__ __forceinline__ void cp16(const ushort* g, ushort* l) {
  // async global->LDS, 16B per lane; LDS dest = wave-uniform base + lane*16
  __builtin_amdgcn_global_load_lds((as1_u32*)g, (as3_u32*)l, 16, 0, 0);
}

// ---------------- weight convert + transpose: W[K][N] f32 -> WT[N][K] bf16 ----
__global__ __launch_bounds__(256) void wcvt_kernel(const float* __restrict__ W,
                                                   ushort* __restrict__ WT,
                                                   int K, int N) {
  __shared__ float t[32][33];
  int k0 = blockIdx.x * 32, n0 = blockIdx.y * 32;
  int tx = threadIdx.x, ty = threadIdx.y;  // (32,8)
#pragma unroll
  for (int i = 0; i < 32; i += 8)
    t[ty + i][tx] = W[(size_t)(k0 + ty + i) * N + n0 + tx];
  __syncthreads();
#pragma unroll
  for (int i = 0; i < 32; i += 8)
    WT[(size_t)(n0 + ty + i) * K + k0 + tx] = f2bf(t[tx][ty + i]);
}

// ---------------- LayerNorm: row of 1024, one block per row ------------------
__global__ __launch_bounds__(256) void ln_kernel(const float* in,
                                                 const float* __restrict__ g,
                                                 const float* __restrict__ bb,
                                                 float* of, ushort* ob) {
  int row = blockIdx.x;
  int t = threadIdx.x;
  float4 x = reinterpret_cast<const float4*>(in + (size_t)row * Ec)[t];
  float s = x.x + x.y + x.z + x.w;
  float q = x.x * x.x + x.y * x.y + x.z * x.z + x.w * x.w;
#pragma unroll
  for (int o = 32; o > 0; o >>= 1) {
    s += __shfl_down(s, o);
    q += __shfl_down(q, o);
  }
  __shared__ float red[10];
  int wv = t >> 6;
  if ((t & 63) == 0) { red[wv] = s; red[4 + wv] = q; }
  __syncthreads();
  if (t == 0) {
    float S = red[0] + red[1] + red[2] + red[3];
    float Q = red[4] + red[5] + red[6] + red[7];
    float mu = S * (1.f / Ec);
    float var = Q * (1.f / Ec) - mu * mu;
    red[8] = mu;
    red[9] = rsqrtf(var + 1e-5f);
  }
  __syncthreads();
  float mu = red[8], rs = red[9];
  float4 gg = reinterpret_cast<const float4*>(g)[t];
  float4 b4 = reinterpret_cast<const float4*>(bb)[t];
  float4 y;
  y.x = (x.x - mu) * rs * gg.x + b4.x;
  y.y = (x.y - mu) * rs * gg.y + b4.y;
  y.z = (x.z - mu) * rs * gg.z + b4.z;
  y.w = (x.w - mu) * rs * gg.w + b4.w;
  reinterpret_cast<float4*>(of + (size_t)row * Ec)[t] = y;
  uint2 u;
  u.x = pkbf(y.x, y.y);
  u.y = pkbf(y.z, y.w);
  reinterpret_cast<uint2*>(ob + (size_t)row * Ec)[t] = u;
}

// ---------------- GEMM 128x128: BK=64, LDS dbuf, counted vmcnt(8) ------------
// MODE 0: fused QKV; MODE 1: f32 acc+bias+resid; MODE 2: bf16 gelu(acc+bias)
template <int MODE>
__global__ __launch_bounds__(256, 2) void gemm_kernel(
    int M, int N, int K, const ushort* __restrict__ A,
    const ushort* __restrict__ BT, const float* __restrict__ b0,
    const float* __restrict__ b1, const float* __restrict__ b2,
    const float* resid, float* outF, ushort* o0, ushort* o1, ushort* o2,
    float qscale) {
  __shared__ __align__(16) ushort As[2][128 * 64];
  __shared__ __align__(16) ushort Bs[2][128 * 64];
  const int tid = threadIdx.x;
  const int lane = tid & 63, wave = tid >> 6;
  const int wr = wave >> 1, wc = wave & 1;
  const int fr = lane & 15, fq = lane >> 4;
  const int nx = gridDim.x;
  int flat = blockIdx.x + nx * blockIdx.y;
  int cpx = (nx * gridDim.y) >> 3;
  int work = (flat & 7) * cpx + (flat >> 3);
  const int n0 = (work % nx) * 128, m0 = (work / nx) * 128;

  f32x4 acc[4][4];
#pragma unroll
  for (int i = 0; i < 4; i++)
#pragma unroll
    for (int j = 0; j < 4; j++) acc[i][j] = f32x4{0.f, 0.f, 0.f, 0.f};

  const int srow = tid >> 3;   // 0..31 (+32 per chunk)
  const int sslot = tid & 7;   // 16B slot within 128B row

  auto STAGE = [&](int p, int k0) {
#pragma unroll
    for (int c = 0; c < 4; ++c) {
      int row = c * 32 + srow;
      int scol = (sslot ^ (2 * (row & 3))) * 8;  // inverse-swizzled source
      cp16(A + (size_t)(m0 + row) * K + k0 + scol,
           &As[p][(c * 256 + wave * 64) * 8]);
      cp16(BT + (size_t)(n0 + row) * K + k0 + scol,
           &Bs[p][(c * 256 + wave * 64) * 8]);
    }
  };

  STAGE(0, 0);
  const int nt = K >> 6;
  for (int kt = 0; kt < nt; ++kt) {
    const int p = kt & 1;
    if (kt + 1 < nt) {
      STAGE(p ^ 1, (kt + 1) << 6);
      asm volatile("s_waitcnt vmcnt(8)" ::: "memory");  // tile kt landed
    } else {
      asm volatile("s_waitcnt vmcnt(0)" ::: "memory");
    }
    __builtin_amdgcn_s_barrier();
#pragma unroll
    for (int kk = 0; kk < 2; ++kk) {
      bfv8 af[4], bf[4];
#pragma unroll
      for (int m = 0; m < 4; m++) {
        int row = wr * 64 + m * 16 + fr;
        af[m] = *reinterpret_cast<const bfv8*>(
            &As[p][row * 64 + ((kk * 32 + fq * 8) ^ ((fr & 3) << 4))]);
      }
#pragma unroll
      for (int n = 0; n < 4; n++) {
        int row = wc * 64 + n * 16 + fr;
        bf[n] = *reinterpret_cast<const bfv8*>(
            &Bs[p][row * 64 + ((kk * 32 + fq * 8) ^ ((fr & 3) << 4))]);
      }
      __builtin_amdgcn_s_setprio(1);
#pragma unroll
      for (int m = 0; m < 4; m++)
#pragma unroll
        for (int n = 0; n < 4; n++)
          acc[m][n] =
              __builtin_amdgcn_mfma_f32_16x16x32_bf16(af[m], bf[n], acc[m][n], 0, 0, 0);
      __builtin_amdgcn_s_setprio(0);
    }
    __builtin_amdgcn_sched_barrier(0);
    __builtin_amdgcn_s_barrier();
  }

#pragma unroll
  for (int m = 0; m < 4; m++) {
#pragma unroll
    for (int n = 0; n < 4; n++) {
      const int row0 = m0 + wr * 64 + m * 16 + fq * 4;
      const int col = n0 + wc * 64 + n * 16 + fr;
      if constexpr (MODE == 0) {
        const int region = col >> 10, c1 = col & (Ec - 1);
        const int b = row0 >> 11, s0 = row0 & (Sc - 1);
        const int h = c1 >> 6, d = c1 & (Dc - 1);
        const float bb = (region == 0 ? b0 : region == 1 ? b1 : b2)[c1];
        if (region == 2) {
          uint2 u;
          u.x = pkbf(acc[m][n][0] + bb, acc[m][n][1] + bb);
          u.y = pkbf(acc[m][n][2] + bb, acc[m][n][3] + bb);
          *reinterpret_cast<uint2*>(
              &o2[(((size_t)b * Hc + h) * Dc + d) * Sc + s0]) = u;
        } else {
          ushort* dst = region ? o1 : o0;
          const float sc = region ? 1.f : qscale;
#pragma unroll
          for (int r = 0; r < 4; r++)
            dst[(((size_t)b * Hc + h) * Sc + s0 + r) * Dc + d] =
                f2bf((acc[m][n][r] + bb) * sc);
        }
      } else {
        const float bb = b0[col];
#pragma unroll
        for (int r = 0; r < 4; r++) {
          int row = row0 + r;
          float vacc = acc[m][n][r] + bb;
          if constexpr (MODE == 1) {
            size_t idx = (size_t)row * N + col;
            outF[idx] = vacc + resid[idx];
          } else {
            vacc = 0.5f * vacc * (1.f + erff(vacc * 0.70710678118f));
            o0[(size_t)row * N + col] = f2bf(vacc);
          }
        }
      }
    }
  }
}

// ======== 256x256 8-wave 4-phase GEMM (W1 only: grid 256 = exactly 1/CU) ====
// MODE 2: bf16 gelu(acc+bias)
template <int MODE>
__global__ __launch_bounds__(512, 2) void gemm256_kernel(
    int M, int N, int K, const ushort* __restrict__ A,
    const ushort* __restrict__ BT, const float* __restrict__ b0,
    ushort* o0, float qscale) {
  __shared__ __align__(16) ushort As[2][256 * 64];
  __shared__ __align__(16) ushort Bs[2][256 * 64];
  const int tid = threadIdx.x;
  const int lane = tid & 63, wave = tid >> 6;  // 8 waves
  const int wr = wave >> 2, wc = wave & 3;     // 2 x 4
  const int fr = lane & 15, fq = lane >> 4;
  const int nx = gridDim.x;
  int flat = blockIdx.x + nx * blockIdx.y;
  int cpx = (nx * gridDim.y) >> 3;
  int work = (flat & 7) * cpx + (flat >> 3);
  const int n0 = (work % nx) * 256, m0 = (work / nx) * 256;

  f32x4 acc[8][4];
#pragma unroll
  for (int i = 0; i < 8; i++)
#pragma unroll
    for (int j = 0; j < 4; j++) acc[i][j] = f32x4{0.f, 0.f, 0.f, 0.f};

  const int srow = tid >> 3;  // 0..63
  const int sslot = tid & 7;

  auto STAGE = [&](int p, int k0) {
#pragma unroll
    for (int c = 0; c < 4; ++c) {
      int row = c * 64 + srow;
      int scol = (sslot ^ (row & 7)) * 8;  // inverse-swizzled source
      cp16(A + (size_t)(m0 + row) * K + k0 + scol,
           &As[p][(c * 64 + wave * 8) * 64]);
      cp16(BT + (size_t)(n0 + row) * K + k0 + scol,
           &Bs[p][(c * 64 + wave * 8) * 64]);
    }
  };

  STAGE(0, 0);
  const int nt = K >> 6;
  for (int kt = 0; kt < nt; ++kt) {
    const int p = kt & 1;
    if (kt + 1 < nt) {
      STAGE(p ^ 1, (kt + 1) << 6);
      asm volatile("s_waitcnt vmcnt(8)" ::: "memory");  // tile kt landed
    } else {
      asm volatile("s_waitcnt vmcnt(0)" ::: "memory");
    }
    __builtin_amdgcn_s_barrier();
#pragma unroll
    for (int kk = 0; kk < 2; ++kk) {
      bfv8 bfr[4];
#pragma unroll
      for (int n = 0; n < 4; ++n) {
        int row = wc * 64 + n * 16 + fr;
        bfr[n] = *reinterpret_cast<const bfv8*>(
            &Bs[p][row * 64 + (((kk * 4 + fq) ^ (row & 7)) * 8)]);
      }
#pragma unroll
      for (int mh = 0; mh < 2; ++mh) {
        bfv8 af[4];
#pragma unroll
        for (int mm = 0; mm < 4; ++mm) {
          int row = wr * 128 + (mh * 4 + mm) * 16 + fr;
          af[mm] = *reinterpret_cast<const bfv8*>(
              &As[p][row * 64 + (((kk * 4 + fq) ^ (row & 7)) * 8)]);
        }
        __builtin_amdgcn_s_setprio(1);
#pragma unroll
        for (int mm = 0; mm < 4; ++mm)
#pragma unroll
          for (int n = 0; n < 4; ++n)
            acc[mh * 4 + mm][n] = __builtin_amdgcn_mfma_f32_16x16x32_bf16(
                af[mm], bfr[n], acc[mh * 4 + mm][n], 0, 0, 0);
        __builtin_amdgcn_s_setprio(0);
        if (!(kk == 1 && mh == 1)) __builtin_amdgcn_s_barrier();  // phase edge
      }
    }
    __builtin_amdgcn_sched_barrier(0);
    __builtin_amdgcn_s_barrier();  // tile edge: all reads of buf p done
  }

#pragma unroll
  for (int m = 0; m < 8; m++) {
#pragma unroll
    for (int n = 0; n < 4; n++) {
      const int row0 = m0 + wr * 128 + m * 16 + fq * 4;
      const int col = n0 + wc * 64 + n * 16 + fr;
      const float bb = b0[col];
#pragma unroll
      for (int r = 0; r < 4; r++) {
        float vacc = acc[m][n][r] + bb;
        vacc = 0.5f * vacc * (1.f + erff(vacc * 0.70710678118f));
        o0[(size_t)(row0 + r) * N + col] = f2bf(vacc);
      }
    }
  }
}

// ---------------- Flash attention (32 q-rows per wave, 128 per block) --------
// (unchanged from R11/R12)
__global__ __launch_bounds__(256) void attn_kernel(const ushort* __restrict__ q,
                                                   const ushort* __restrict__ k,
                                                   const ushort* __restrict__ vt,
                                                   ushort* __restrict__ o) {
  int flat = blockIdx.x;                     // 1024 blocks
  int swz = (flat & 7) * 128 + (flat >> 3);  // XCD-chunked: 8 heads per XCD
  const int qb = swz & 15;                   // 16 q-blocks of 128 rows
  const int bh = swz >> 4;
  const int tid = threadIdx.x, lane = tid & 63, wave = tid >> 6;
  const int fr = lane & 15, fq = lane >> 4;
  const size_t base = (size_t)bh * Sc * Dc;
  const int q0 = qb * 128 + wave * 32;

  __shared__ __align__(16) ushort Ks[2][64 * 64];  // [key][d], XOR-swizzled
  __shared__ __align__(16) ushort Vt[2][64 * 64];  // [d][key], XOR-swizzled
  __shared__ __align__(16) ushort Ps[4][16 * 64];  // per-wave P, XOR-swizzled

  bfv8 qf0[2], qf1[2];
#pragma unroll
  for (int f = 0; f < 2; ++f) {
    const ushort* qp = q + base + (size_t)(q0 + f * 16 + fr) * Dc + fq * 8;
    qf0[f] = *reinterpret_cast<const bfv8*>(qp);
    qf1[f] = *reinterpret_cast<const bfv8*>(qp + 32);
  }

  const bfv8 ones = __builtin_bit_cast(bfv8, uint4{0x3F803F80u, 0x3F803F80u,
                                                  0x3F803F80u, 0x3F803F80u});

  f32x4 oacc[2][4];  // [frag][dtile]
  f32x4 oaccL[2];    // row-sum accumulator (l)
#pragma unroll
  for (int f = 0; f < 2; ++f) {
    oaccL[f] = f32x4{0.f, 0.f, 0.f, 0.f};
#pragma unroll
    for (int d = 0; d < 4; ++d) oacc[f][d] = f32x4{0.f, 0.f, 0.f, 0.f};
  }
  float mrow[2] = {-3e38f, -3e38f};

  const int r8 = tid >> 3;  // staging row 0..31
  const int c8 = tid & 7;   // staging 16B chunk

  auto STAGE = [&](int p, int key0) {
#pragma unroll
    for (int i = 0; i < 2; ++i) {
      int row = i * 32 + r8;
      int sc = (c8 ^ (row & 7)) * 8;  // inverse-swizzled source
      cp16(k + base + (size_t)(key0 + row) * Dc + sc,
           &Ks[p][i * 2048 + wave * 512]);
      cp16(vt + base + (size_t)row * Sc + key0 + sc,
           &Vt[p][i * 2048 + wave * 512]);
    }
  };

  const int sA = (fq ^ (fr & 7)) * 8;
  const int sB = ((fq + 4) ^ (fr & 7)) * 8;

  const int pswz = 2 * (fr & 7);
  const int pr0 = fr * 64 + ((fq * 2) ^ pswz) * 4;
  const int pr1 = fr * 64 + ((fq * 2 + 8) ^ pswz) * 4;

  STAGE(0, 0);
  constexpr int NT = Sc / 64;
  for (int kt = 0; kt < NT; ++kt) {
    const int p = kt & 1;
    if (kt + 1 < NT) {
      STAGE(p ^ 1, (kt + 1) * 64);
      asm volatile("s_waitcnt vmcnt(4)" ::: "memory");
    } else {
      asm volatile("s_waitcnt vmcnt(0)" ::: "memory");
    }
    __builtin_amdgcn_s_barrier();

    bfv8 kf0[4], kf1[4], vf0[4], vf1[4];
#pragma unroll
    for (int t = 0; t < 4; ++t) {
      int e = (t * 16 + fr) * 64;
      kf0[t] = *reinterpret_cast<const bfv8*>(&Ks[p][e + sA]);
      kf1[t] = *reinterpret_cast<const bfv8*>(&Ks[p][e + sB]);
      vf0[t] = *reinterpret_cast<const bfv8*>(&Vt[p][e + sA]);
      vf1[t] = *reinterpret_cast<const bfv8*>(&Vt[p][e + sB]);
    }

#pragma unroll
    for (int f = 0; f < 2; ++f) {
      f32x4 sf[4];
      __builtin_amdgcn_s_setprio(1);
#pragma unroll
      for (int t = 0; t < 4; ++t) {
        sf[t] = f32x4{0.f, 0.f, 0.f, 0.f};
        sf[t] = __builtin_amdgcn_mfma_f32_16x16x32_bf16(kf0[t], qf0[f], sf[t], 0, 0, 0);
        sf[t] = __builtin_amdgcn_mfma_f32_16x16x32_bf16(kf1[t], qf1[f], sf[t], 0, 0, 0);
      }
      __builtin_amdgcn_s_setprio(0);
      float mt0 = fmaxf(fmaxf(sf[0][0], sf[0][1]), fmaxf(sf[0][2], sf[0][3]));
      float mt1 = fmaxf(fmaxf(sf[1][0], sf[1][1]), fmaxf(sf[1][2], sf[1][3]));
      float mt2 = fmaxf(fmaxf(sf[2][0], sf[2][1]), fmaxf(sf[2][2], sf[2][3]));
      float mt3 = fmaxf(fmaxf(sf[3][0], sf[3][1]), fmaxf(sf[3][2], sf[3][3]));
      float pmax = fmaxf(fmaxf(mt0, mt1), fmaxf(mt2, mt3));
      float m = mrow[f];
      float mnew = m;
      if (!__all(pmax <= m + 8.f)) {
        float mt = fmaxf(pmax, __shfl_xor(pmax, 16));
        mt = fmaxf(mt, __shfl_xor(mt, 32));
        mnew = fmaxf(m, mt);
        float alpha = __builtin_amdgcn_exp2f(m - mnew);
        float ar[4];
#pragma unroll
        for (int r = 0; r < 4; ++r) ar[r] = __shfl(alpha, fq * 4 + r);
#pragma unroll
        for (int d = 0; d < 4; ++d)
#pragma unroll
          for (int r = 0; r < 4; ++r) oacc[f][d][r] *= ar[r];
#pragma unroll
        for (int r = 0; r < 4; ++r) oaccL[f][r] *= ar[r];
        mrow[f] = mnew;
      }
      ushort* pw = &Ps[wave][0];
#pragma unroll
      for (int t = 0; t < 4; ++t) {
        uint2 pu;
        pu.x = pkbf(__builtin_amdgcn_exp2f(sf[t][0] - mnew),
                    __builtin_amdgcn_exp2f(sf[t][1] - mnew));
        pu.y = pkbf(__builtin_amdgcn_exp2f(sf[t][2] - mnew),
                    __builtin_amdgcn_exp2f(sf[t][3] - mnew));
        int us = fr * 64 + ((t * 4 + fq) ^ pswz) * 4;
        *reinterpret_cast<uint2*>(&pw[us]) = pu;
      }
      bfv8 pf0 = *reinterpret_cast<const bfv8*>(&pw[pr0]);
      bfv8 pf1 = *reinterpret_cast<const bfv8*>(&pw[pr1]);
      __builtin_amdgcn_s_setprio(1);
#pragma unroll
      for (int d = 0; d < 4; ++d) {
        oacc[f][d] = __builtin_amdgcn_mfma_f32_16x16x32_bf16(pf0, vf0[d], oacc[f][d], 0, 0, 0);
        oacc[f][d] = __builtin_amdgcn_mfma_f32_16x16x32_bf16(pf1, vf1[d], oacc[f][d], 0, 0, 0);
      }
      oaccL[f] = __builtin_amdgcn_mfma_f32_16x16x32_bf16(pf0, ones, oaccL[f], 0, 0, 0);
      oaccL[f] = __builtin_amdgcn_mfma_f32_16x16x32_bf16(pf1, ones, oaccL[f], 0, 0, 0);
      __builtin_amdgcn_s_setprio(0);
    }
    __builtin_amdgcn_sched_barrier(0);
    __builtin_amdgcn_s_barrier();
  }

  const int b = bh >> 4, h = bh & 15;
#pragma unroll
  for (int f = 0; f < 2; ++f) {
    float linv[4];
#pragma unroll
    for (int r = 0; r < 4; ++r) linv[r] = 1.f / oaccL[f][r];
#pragma unroll
    for (int d = 0; d < 4; ++d)
#pragma unroll
      for (int r = 0; r < 4; ++r) {
        int sIdx = q0 + f * 16 + fq * 4 + r;
        o[((size_t)(b * Sc + sIdx)) * Ec + h * 64 + d * 16 + fr] =
            f2bf(oacc[f][d][r] * linv[r]);
      }
  }
}

// -----------------------------------------------------------------------------
extern "C" void kernel_launch(void* const* d_in, const int* in_sizes, int n_in,
                              void* d_out, int out_size, void* d_ws, size_t ws_size,
                              hipStream_t stream) {
  const float* inp = (const float*)d_in[0];
  const float* ln1g = (const float*)d_in[1];
  const float* ln1b = (const float*)d_in[2];
  const float* Wq = (const float*)d_in[3];
  const float* bq = (const float*)d_in[4];
  const float* Wk = (const float*)d_in[5];
  const float* bk = (const float*)d_in[6];
  const float* Wv = (const float*)d_in[7];
  const float* bv = (const float*)d_in[8];
  const float* Wo = (const float*)d_in[9];
  const float* bo = (const float*)d_in[10];
  const float* ln2g = (const float*)d_in[11];
  const float* ln2b = (const float*)d_in[12];
  const float* W1 = (const float*)d_in[13];
  const float* b1 = (const float*)d_in[14];
  const float* W2 = (const float*)d_in[15];
  const float* b2 = (const float*)d_in[16];

  char* wsb = (char*)d_ws;
  size_t off = 0;
  auto alloc = [&](size_t bytes) {
    char* p = wsb + off;
    off += (bytes + 255) & ~(size_t)255;
    return p;
  };
  float* xf = (float*)alloc((size_t)Mc * Ec * 4);
  ushort* xb = (ushort*)alloc((size_t)Mc * Ec * 2);
  ushort* qbuf = (ushort*)alloc((size_t)Mc * Ec * 2);
  ushort* kbuf = (ushort*)alloc((size_t)Mc * Ec * 2);
  ushort* vtbuf = (ushort*)alloc((size_t)Mc * Ec * 2);
  ushort* abuf = (ushort*)alloc((size_t)Mc * Ec * 2);
  ushort* h1 = (ushort*)alloc((size_t)Mc * 2 * Ec * 2);
  ushort* WqkvT = (ushort*)alloc((size_t)3 * Ec * Ec * 2);  // [3E][E]
  ushort* WoT = (ushort*)alloc((size_t)Ec * Ec * 2);
  ushort* W1T = (ushort*)alloc((size_t)Ec * 2 * Ec * 2);
  ushort* W2T = (ushort*)alloc((size_t)Ec * 2 * Ec * 2);
  (void)in_sizes; (void)n_in; (void)out_size; (void)ws_size;

  dim3 tb(32, 8);
  wcvt_kernel<<<dim3(Ec / 32, Ec / 32), tb, 0, stream>>>(Wq, WqkvT, Ec, Ec);
  wcvt_kernel<<<dim3(Ec / 32, Ec / 32), tb, 0, stream>>>(Wk, WqkvT + (size_t)Ec * Ec, Ec, Ec);
  wcvt_kernel<<<dim3(Ec / 32, Ec / 32), tb, 0, stream>>>(Wv, WqkvT + (size_t)2 * Ec * Ec, Ec, Ec);
  wcvt_kernel<<<dim3(Ec / 32, Ec / 32), tb, 0, stream>>>(Wo, WoT, Ec, Ec);
  wcvt_kernel<<<dim3(Ec / 32, 2 * Ec / 32), tb, 0, stream>>>(W1, W1T, Ec, 2 * Ec);
  wcvt_kernel<<<dim3(2 * Ec / 32, Ec / 32), tb, 0, stream>>>(W2, W2T, 2 * Ec, Ec);

  ln_kernel<<<Mc, 256, 0, stream>>>(inp, ln1g, ln1b, xf, xb);

  // Fused QKV on the 128² kernel (grid 24x64 = 1536 = 6/CU exact, no tail).
  // Q pre-scale (1/sqrt(D))*log2(e) -> exp2-domain softmax
  gemm_kernel<0><<<dim3(3 * Ec / 128, Mc / 128), 256, 0, stream>>>(
      Mc, 3 * Ec, Ec, xb, WqkvT, bq, bk, bv, nullptr, nullptr, qbuf, kbuf,
      vtbuf, 0.18033688f);

  attn_kernel<<<Bc * Hc * (Sc / 128), 256, 0, stream>>>(qbuf, kbuf, vtbuf, abuf);

  gemm_kernel<1><<<dim3(Ec / 128, Mc / 128), 256, 0, stream>>>(
      Mc, Ec, Ec, abuf, WoT, bo, nullptr, nullptr, xf, xf, nullptr, nullptr,
      nullptr, 1.f);

  ln_kernel<<<Mc, 256, 0, stream>>>(xf, ln2g, ln2b, xf, xb);

  // W1 + GELU on the 256² 4-phase kernel (grid 8x32 = 256 = exactly 1/CU)
  gemm256_kernel<2><<<dim3(2 * Ec / 256, Mc / 256), 512, 0, stream>>>(
      Mc, 2 * Ec, Ec, xb, W1T, b1, h1, 1.f);

  gemm_kernel<1><<<dim3(Ec / 128, Mc / 128), 256, 0, stream>>>(
      Mc, Ec, 2 * Ec, h1, W2T, b2, nullptr, nullptr, xf, (float*)d_out,
      nullptr, nullptr, nullptr, 1.f);
}

// Round 15
// 365.042 us; speedup vs baseline: 1.0583x; 1.0267x over previous
//
#include <hip/hip_runtime.h>
#include <hip/hip_bf16.h>

typedef float f32x4 __attribute__((ext_vector_type(4)));
typedef __bf16 bfv8 __attribute__((ext_vector_type(8)));

constexpr int Bc = 4, Sc = 2048, Ec = 1024, Hc = 16, Dc = 64;
constexpr int Mc = Bc * Sc;  // 8192 rows

__device__ __forceinline__ uint pkbf(float lo, float hi) {
  uint r;
  asm("v_cvt_pk_bf16_f32 %0, %1, %2" : "=v"(r) : "v"(lo), "v"(hi));
  return r;
}
__device__ __forceinline__ ushort f2bf(float f) {
  __hip_bfloat16 h = __float2bfloat16(f);
  return __builtin_bit_cast(ushort, h);
}

typedef __attribute__((address_space(1))) unsigned int as1_u32;
typedef __attribute__((address_space(3))) unsigned int as3_u32;
__device__ __forceinline__ void cp16(const ushort* g, ushort* l) {
  // async global->LDS, 16B per lane; LDS dest = wave-uniform base + lane*16
  __builtin_amdgcn_global_load_lds((as1_u32*)g, (as3_u32*)l, 16, 0, 0);
}

// ---------------- all-weights convert+transpose in ONE launch ----------------
// W[K][N] f32 -> WT[N][K] bf16, 32x32 tiles, if-chain block dispatch.
__global__ __launch_bounds__(256) void wcvt_all_kernel(
    const float* __restrict__ Wq, const float* __restrict__ Wk,
    const float* __restrict__ Wv, const float* __restrict__ Wo,
    const float* __restrict__ W1, const float* __restrict__ W2,
    ushort* __restrict__ WqkvT, ushort* __restrict__ WoT,
    ushort* __restrict__ W1T, ushort* __restrict__ W2T) {
  int bid = blockIdx.x;
  const float* W;
  ushort* WT;
  int K, N;
  if (bid < 1024) {
    W = Wq; WT = WqkvT; K = 1024; N = 1024;
  } else if (bid < 2048) {
    W = Wk; WT = WqkvT + (size_t)1024 * 1024; K = 1024; N = 1024; bid -= 1024;
  } else if (bid < 3072) {
    W = Wv; WT = WqkvT + (size_t)2 * 1024 * 1024; K = 1024; N = 1024; bid -= 2048;
  } else if (bid < 4096) {
    W = Wo; WT = WoT; K = 1024; N = 1024; bid -= 3072;
  } else if (bid < 6144) {
    W = W1; WT = W1T; K = 1024; N = 2048; bid -= 4096;
  } else {
    W = W2; WT = W2T; K = 2048; N = 1024; bid -= 6144;
  }
  const int nbx = K / 32;
  const int k0 = (bid % nbx) * 32, n0 = (bid / nbx) * 32;
  __shared__ float t[32][33];
  int tx = threadIdx.x, ty = threadIdx.y;  // (32,8)
#pragma unroll
  for (int i = 0; i < 32; i += 8)
    t[ty + i][tx] = W[(size_t)(k0 + ty + i) * N + n0 + tx];
  __syncthreads();
#pragma unroll
  for (int i = 0; i < 32; i += 8)
    WT[(size_t)(n0 + ty + i) * K + k0 + tx] = f2bf(t[tx][ty + i]);
}

// ---------------- LayerNorm: row of 1024, one block per row ------------------
__global__ __launch_bounds__(256) void ln_kernel(const float* in,
                                                 const float* __restrict__ g,
                                                 const float* __restrict__ bb,
                                                 float* of, ushort* ob) {
  int row = blockIdx.x;
  int t = threadIdx.x;
  float4 x = reinterpret_cast<const float4*>(in + (size_t)row * Ec)[t];
  float s = x.x + x.y + x.z + x.w;
  float q = x.x * x.x + x.y * x.y + x.z * x.z + x.w * x.w;
#pragma unroll
  for (int o = 32; o > 0; o >>= 1) {
    s += __shfl_down(s, o);
    q += __shfl_down(q, o);
  }
  __shared__ float red[10];
  int wv = t >> 6;
  if ((t & 63) == 0) { red[wv] = s; red[4 + wv] = q; }
  __syncthreads();
  if (t == 0) {
    float S = red[0] + red[1] + red[2] + red[3];
    float Q = red[4] + red[5] + red[6] + red[7];
    float mu = S * (1.f / Ec);
    float var = Q * (1.f / Ec) - mu * mu;
    red[8] = mu;
    red[9] = rsqrtf(var + 1e-5f);
  }
  __syncthreads();
  float mu = red[8], rs = red[9];
  float4 gg = reinterpret_cast<const float4*>(g)[t];
  float4 b4 = reinterpret_cast<const float4*>(bb)[t];
  float4 y;
  y.x = (x.x - mu) * rs * gg.x + b4.x;
  y.y = (x.y - mu) * rs * gg.y + b4.y;
  y.z = (x.z - mu) * rs * gg.z + b4.z;
  y.w = (x.w - mu) * rs * gg.w + b4.w;
  reinterpret_cast<float4*>(of + (size_t)row * Ec)[t] = y;
  uint2 u;
  u.x = pkbf(y.x, y.y);
  u.y = pkbf(y.z, y.w);
  reinterpret_cast<uint2*>(ob + (size_t)row * Ec)[t] = u;
}

// ---------------- GEMM 128x128: BK=64, LDS dbuf, counted vmcnt(8) ------------
// MODE 0: fused QKV; MODE 1: f32 acc+bias+resid; MODE 2: bf16 gelu(acc+bias)
template <int MODE>
__global__ __launch_bounds__(256, 2) void gemm_kernel(
    int M, int N, int K, const ushort* __restrict__ A,
    const ushort* __restrict__ BT, const float* __restrict__ b0,
    const float* __restrict__ b1, const float* __restrict__ b2,
    const float* resid, float* outF, ushort* o0, ushort* o1, ushort* o2,
    float qscale) {
  __shared__ __align__(16) ushort As[2][128 * 64];
  __shared__ __align__(16) ushort Bs[2][128 * 64];
  const int tid = threadIdx.x;
  const int lane = tid & 63, wave = tid >> 6;
  const int wr = wave >> 1, wc = wave & 1;
  const int fr = lane & 15, fq = lane >> 4;
  const int nx = gridDim.x;
  int flat = blockIdx.x + nx * blockIdx.y;
  int cpx = (nx * gridDim.y) >> 3;
  int work = (flat & 7) * cpx + (flat >> 3);
  const int n0 = (work % nx) * 128, m0 = (work / nx) * 128;

  f32x4 acc[4][4];
#pragma unroll
  for (int i = 0; i < 4; i++)
#pragma unroll
    for (int j = 0; j < 4; j++) acc[i][j] = f32x4{0.f, 0.f, 0.f, 0.f};

  const int srow = tid >> 3;   // 0..31 (+32 per chunk)
  const int sslot = tid & 7;   // 16B slot within 128B row

  auto STAGE = [&](int p, int k0) {
#pragma unroll
    for (int c = 0; c < 4; ++c) {
      int row = c * 32 + srow;
      int scol = (sslot ^ (2 * (row & 3))) * 8;  // inverse-swizzled source
      cp16(A + (size_t)(m0 + row) * K + k0 + scol,
           &As[p][(c * 256 + wave * 64) * 8]);
      cp16(BT + (size_t)(n0 + row) * K + k0 + scol,
           &Bs[p][(c * 256 + wave * 64) * 8]);
    }
  };

  STAGE(0, 0);
  const int nt = K >> 6;
  for (int kt = 0; kt < nt; ++kt) {
    const int p = kt & 1;
    if (kt + 1 < nt) {
      STAGE(p ^ 1, (kt + 1) << 6);
      asm volatile("s_waitcnt vmcnt(8)" ::: "memory");  // tile kt landed
    } else {
      asm volatile("s_waitcnt vmcnt(0)" ::: "memory");
    }
    __builtin_amdgcn_s_barrier();
#pragma unroll
    for (int kk = 0; kk < 2; ++kk) {
      bfv8 af[4], bf[4];
#pragma unroll
      for (int m = 0; m < 4; m++) {
        int row = wr * 64 + m * 16 + fr;
        af[m] = *reinterpret_cast<const bfv8*>(
            &As[p][row * 64 + ((kk * 32 + fq * 8) ^ ((fr & 3) << 4))]);
      }
#pragma unroll
      for (int n = 0; n < 4; n++) {
        int row = wc * 64 + n * 16 + fr;
        bf[n] = *reinterpret_cast<const bfv8*>(
            &Bs[p][row * 64 + ((kk * 32 + fq * 8) ^ ((fr & 3) << 4))]);
      }
      __builtin_amdgcn_s_setprio(1);
#pragma unroll
      for (int m = 0; m < 4; m++)
#pragma unroll
        for (int n = 0; n < 4; n++)
          acc[m][n] =
              __builtin_amdgcn_mfma_f32_16x16x32_bf16(af[m], bf[n], acc[m][n], 0, 0, 0);
      __builtin_amdgcn_s_setprio(0);
    }
    __builtin_amdgcn_sched_barrier(0);
    __builtin_amdgcn_s_barrier();
  }

#pragma unroll
  for (int m = 0; m < 4; m++) {
#pragma unroll
    for (int n = 0; n < 4; n++) {
      const int row0 = m0 + wr * 64 + m * 16 + fq * 4;
      const int col = n0 + wc * 64 + n * 16 + fr;
      if constexpr (MODE == 0) {
        const int region = col >> 10, c1 = col & (Ec - 1);
        const int b = row0 >> 11, s0 = row0 & (Sc - 1);
        const int h = c1 >> 6, d = c1 & (Dc - 1);
        const float bb = (region == 0 ? b0 : region == 1 ? b1 : b2)[c1];
        if (region == 2) {
          uint2 u;
          u.x = pkbf(acc[m][n][0] + bb, acc[m][n][1] + bb);
          u.y = pkbf(acc[m][n][2] + bb, acc[m][n][3] + bb);
          *reinterpret_cast<uint2*>(
              &o2[(((size_t)b * Hc + h) * Dc + d) * Sc + s0]) = u;
        } else {
          ushort* dst = region ? o1 : o0;
          const float sc = region ? 1.f : qscale;
#pragma unroll
          for (int r = 0; r < 4; r++)
            dst[(((size_t)b * Hc + h) * Sc + s0 + r) * Dc + d] =
                f2bf((acc[m][n][r] + bb) * sc);
        }
      } else {
        const float bb = b0[col];
#pragma unroll
        for (int r = 0; r < 4; r++) {
          int row = row0 + r;
          float vacc = acc[m][n][r] + bb;
          if constexpr (MODE == 1) {
            size_t idx = (size_t)row * N + col;
            outF[idx] = vacc + resid[idx];
          } else {
            vacc = 0.5f * vacc * (1.f + erff(vacc * 0.70710678118f));
            o0[(size_t)row * N + col] = f2bf(vacc);
          }
        }
      }
    }
  }
}

// ======== 256x256 8-wave 4-phase GEMM (W1 only: grid 256 = exactly 1/CU) ====
// MODE 2: bf16 gelu(acc+bias)
template <int MODE>
__global__ __launch_bounds__(512, 2) void gemm256_kernel(
    int M, int N, int K, const ushort* __restrict__ A,
    const ushort* __restrict__ BT, const float* __restrict__ b0,
    ushort* o0, float qscale) {
  __shared__ __align__(16) ushort As[2][256 * 64];
  __shared__ __align__(16) ushort Bs[2][256 * 64];
  const int tid = threadIdx.x;
  const int lane = tid & 63, wave = tid >> 6;  // 8 waves
  const int wr = wave >> 2, wc = wave & 3;     // 2 x 4
  const int fr = lane & 15, fq = lane >> 4;
  const int nx = gridDim.x;
  int flat = blockIdx.x + nx * blockIdx.y;
  int cpx = (nx * gridDim.y) >> 3;
  int work = (flat & 7) * cpx + (flat >> 3);
  const int n0 = (work % nx) * 256, m0 = (work / nx) * 256;

  f32x4 acc[8][4];
#pragma unroll
  for (int i = 0; i < 8; i++)
#pragma unroll
    for (int j = 0; j < 4; j++) acc[i][j] = f32x4{0.f, 0.f, 0.f, 0.f};

  const int srow = tid >> 3;  // 0..63
  const int sslot = tid & 7;

  auto STAGE = [&](int p, int k0) {
#pragma unroll
    for (int c = 0; c < 4; ++c) {
      int row = c * 64 + srow;
      int scol = (sslot ^ (row & 7)) * 8;  // inverse-swizzled source
      cp16(A + (size_t)(m0 + row) * K + k0 + scol,
           &As[p][(c * 64 + wave * 8) * 64]);
      cp16(BT + (size_t)(n0 + row) * K + k0 + scol,
           &Bs[p][(c * 64 + wave * 8) * 64]);
    }
  };

  STAGE(0, 0);
  const int nt = K >> 6;
  for (int kt = 0; kt < nt; ++kt) {
    const int p = kt & 1;
    if (kt + 1 < nt) {
      STAGE(p ^ 1, (kt + 1) << 6);
      asm volatile("s_waitcnt vmcnt(8)" ::: "memory");  // tile kt landed
    } else {
      asm volatile("s_waitcnt vmcnt(0)" ::: "memory");
    }
    __builtin_amdgcn_s_barrier();
#pragma unroll
    for (int kk = 0; kk < 2; ++kk) {
      bfv8 bfr[4];
#pragma unroll
      for (int n = 0; n < 4; ++n) {
        int row = wc * 64 + n * 16 + fr;
        bfr[n] = *reinterpret_cast<const bfv8*>(
            &Bs[p][row * 64 + (((kk * 4 + fq) ^ (row & 7)) * 8)]);
      }
#pragma unroll
      for (int mh = 0; mh < 2; ++mh) {
        bfv8 af[4];
#pragma unroll
        for (int mm = 0; mm < 4; ++mm) {
          int row = wr * 128 + (mh * 4 + mm) * 16 + fr;
          af[mm] = *reinterpret_cast<const bfv8*>(
              &As[p][row * 64 + (((kk * 4 + fq) ^ (row & 7)) * 8)]);
        }
        __builtin_amdgcn_s_setprio(1);
#pragma unroll
        for (int mm = 0; mm < 4; ++mm)
#pragma unroll
          for (int n = 0; n < 4; ++n)
            acc[mh * 4 + mm][n] = __builtin_amdgcn_mfma_f32_16x16x32_bf16(
                af[mm], bfr[n], acc[mh * 4 + mm][n], 0, 0, 0);
        __builtin_amdgcn_s_setprio(0);
        if (!(kk == 1 && mh == 1)) __builtin_amdgcn_s_barrier();  // phase edge
      }
    }
    __builtin_amdgcn_sched_barrier(0);
    __builtin_amdgcn_s_barrier();  // tile edge: all reads of buf p done
  }

#pragma unroll
  for (int m = 0; m < 8; m++) {
#pragma unroll
    for (int n = 0; n < 4; n++) {
      const int row0 = m0 + wr * 128 + m * 16 + fq * 4;
      const int col = n0 + wc * 64 + n * 16 + fr;
      const float bb = b0[col];
#pragma unroll
      for (int r = 0; r < 4; r++) {
        float vacc = acc[m][n][r] + bb;
        vacc = 0.5f * vacc * (1.f + erff(vacc * 0.70710678118f));
        o0[(size_t)(row0 + r) * N + col] = f2bf(vacc);
      }
    }
  }
}

// ---------------- Flash attention (32 q-rows per wave, 128 per block) --------
// R13-exact (known good): K/V LDS double-buffered, counted vmcnt(4) + raw
// barriers; l-sum via ones-MFMA; pad-free XOR-swizzled Ps. LDS 40960 B.
__global__ __launch_bounds__(256) void attn_kernel(const ushort* __restrict__ q,
                                                   const ushort* __restrict__ k,
                                                   const ushort* __restrict__ vt,
                                                   ushort* __restrict__ o) {
  int flat = blockIdx.x;                     // 1024 blocks
  int swz = (flat & 7) * 128 + (flat >> 3);  // XCD-chunked: 8 heads per XCD
  const int qb = swz & 15;                   // 16 q-blocks of 128 rows
  const int bh = swz >> 4;
  const int tid = threadIdx.x, lane = tid & 63, wave = tid >> 6;
  const int fr = lane & 15, fq = lane >> 4;
  const size_t base = (size_t)bh * Sc * Dc;
  const int q0 = qb * 128 + wave * 32;

  __shared__ __align__(16) ushort Ks[2][64 * 64];  // [key][d], XOR-swizzled
  __shared__ __align__(16) ushort Vt[2][64 * 64];  // [d][key], XOR-swizzled
  __shared__ __align__(16) ushort Ps[4][16 * 64];  // per-wave P, XOR-swizzled

  bfv8 qf0[2], qf1[2];
#pragma unroll
  for (int f = 0; f < 2; ++f) {
    const ushort* qp = q + base + (size_t)(q0 + f * 16 + fr) * Dc + fq * 8;
    qf0[f] = *reinterpret_cast<const bfv8*>(qp);
    qf1[f] = *reinterpret_cast<const bfv8*>(qp + 32);
  }

  const bfv8 ones = __builtin_bit_cast(bfv8, uint4{0x3F803F80u, 0x3F803F80u,
                                                  0x3F803F80u, 0x3F803F80u});

  f32x4 oacc[2][4];  // [frag][dtile]
  f32x4 oaccL[2];    // row-sum accumulator (l)
#pragma unroll
  for (int f = 0; f < 2; ++f) {
    oaccL[f] = f32x4{0.f, 0.f, 0.f, 0.f};
#pragma unroll
    for (int d = 0; d < 4; ++d) oacc[f][d] = f32x4{0.f, 0.f, 0.f, 0.f};
  }
  float mrow[2] = {-3e38f, -3e38f};

  const int r8 = tid >> 3;  // staging row 0..31
  const int c8 = tid & 7;   // staging 16B chunk

  auto STAGE = [&](int p, int key0) {
#pragma unroll
    for (int i = 0; i < 2; ++i) {
      int row = i * 32 + r8;
      int sc = (c8 ^ (row & 7)) * 8;  // inverse-swizzled source
      cp16(k + base + (size_t)(key0 + row) * Dc + sc,
           &Ks[p][i * 2048 + wave * 512]);
      cp16(vt + base + (size_t)row * Sc + key0 + sc,
           &Vt[p][i * 2048 + wave * 512]);
    }
  };

  const int sA = (fq ^ (fr & 7)) * 8;
  const int sB = ((fq + 4) ^ (fr & 7)) * 8;

  const int pswz = 2 * (fr & 7);
  const int pr0 = fr * 64 + ((fq * 2) ^ pswz) * 4;
  const int pr1 = fr * 64 + ((fq * 2 + 8) ^ pswz) * 4;

  STAGE(0, 0);
  constexpr int NT = Sc / 64;
  for (int kt = 0; kt < NT; ++kt) {
    const int p = kt & 1;
    if (kt + 1 < NT) {
      STAGE(p ^ 1, (kt + 1) * 64);
      asm volatile("s_waitcnt vmcnt(4)" ::: "memory");
    } else {
      asm volatile("s_waitcnt vmcnt(0)" ::: "memory");
    }
    __builtin_amdgcn_s_barrier();

    bfv8 kf0[4], kf1[4], vf0[4], vf1[4];
#pragma unroll
    for (int t = 0; t < 4; ++t) {
      int e = (t * 16 + fr) * 64;
      kf0[t] = *reinterpret_cast<const bfv8*>(&Ks[p][e + sA]);
      kf1[t] = *reinterpret_cast<const bfv8*>(&Ks[p][e + sB]);
      vf0[t] = *reinterpret_cast<const bfv8*>(&Vt[p][e + sA]);
      vf1[t] = *reinterpret_cast<const bfv8*>(&Vt[p][e + sB]);
    }

#pragma unroll
    for (int f = 0; f < 2; ++f) {
      f32x4 sf[4];
      __builtin_amdgcn_s_setprio(1);
#pragma unroll
      for (int t = 0; t < 4; ++t) {
        sf[t] = f32x4{0.f, 0.f, 0.f, 0.f};
        sf[t] = __builtin_amdgcn_mfma_f32_16x16x32_bf16(kf0[t], qf0[f], sf[t], 0, 0, 0);
        sf[t] = __builtin_amdgcn_mfma_f32_16x16x32_bf16(kf1[t], qf1[f], sf[t], 0, 0, 0);
      }
      __builtin_amdgcn_s_setprio(0);
      float mt0 = fmaxf(fmaxf(sf[0][0], sf[0][1]), fmaxf(sf[0][2], sf[0][3]));
      float mt1 = fmaxf(fmaxf(sf[1][0], sf[1][1]), fmaxf(sf[1][2], sf[1][3]));
      float mt2 = fmaxf(fmaxf(sf[2][0], sf[2][1]), fmaxf(sf[2][2], sf[2][3]));
      float mt3 = fmaxf(fmaxf(sf[3][0], sf[3][1]), fmaxf(sf[3][2], sf[3][3]));
      float pmax = fmaxf(fmaxf(mt0, mt1), fmaxf(mt2, mt3));
      float m = mrow[f];
      float mnew = m;
      if (!__all(pmax <= m + 8.f)) {
        float mt = fmaxf(pmax, __shfl_xor(pmax, 16));
        mt = fmaxf(mt, __shfl_xor(mt, 32));
        mnew = fmaxf(m, mt);
        float alpha = __builtin_amdgcn_exp2f(m - mnew);
        float ar[4];
#pragma unroll
        for (int r = 0; r < 4; ++r) ar[r] = __shfl(alpha, fq * 4 + r);
#pragma unroll
        for (int d = 0; d < 4; ++d)
#pragma unroll
          for (int r = 0; r < 4; ++r) oacc[f][d][r] *= ar[r];
#pragma unroll
        for (int r = 0; r < 4; ++r) oaccL[f][r] *= ar[r];
        mrow[f] = mnew;
      }
      ushort* pw = &Ps[wave][0];
#pragma unroll
      for (int t = 0; t < 4; ++t) {
        uint2 pu;
        pu.x = pkbf(__builtin_amdgcn_exp2f(sf[t][0] - mnew),
                    __builtin_amdgcn_exp2f(sf[t][1] - mnew));
        pu.y = pkbf(__builtin_amdgcn_exp2f(sf[t][2] - mnew),
                    __builtin_amdgcn_exp2f(sf[t][3] - mnew));
        int us = fr * 64 + ((t * 4 + fq) ^ pswz) * 4;
        *reinterpret_cast<uint2*>(&pw[us]) = pu;
      }
      bfv8 pf0 = *reinterpret_cast<const bfv8*>(&pw[pr0]);
      bfv8 pf1 = *reinterpret_cast<const bfv8*>(&pw[pr1]);
      __builtin_amdgcn_s_setprio(1);
#pragma unroll
      for (int d = 0; d < 4; ++d) {
        oacc[f][d] = __builtin_amdgcn_mfma_f32_16x16x32_bf16(pf0, vf0[d], oacc[f][d], 0, 0, 0);
        oacc[f][d] = __builtin_amdgcn_mfma_f32_16x16x32_bf16(pf1, vf1[d], oacc[f][d], 0, 0, 0);
      }
      oaccL[f] = __builtin_amdgcn_mfma_f32_16x16x32_bf16(pf0, ones, oaccL[f], 0, 0, 0);
      oaccL[f] = __builtin_amdgcn_mfma_f32_16x16x32_bf16(pf1, ones, oaccL[f], 0, 0, 0);
      __builtin_amdgcn_s_setprio(0);
    }
    __builtin_amdgcn_sched_barrier(0);
    __builtin_amdgcn_s_barrier();
  }

  const int b = bh >> 4, h = bh & 15;
#pragma unroll
  for (int f = 0; f < 2; ++f) {
    float linv[4];
#pragma unroll
    for (int r = 0; r < 4; ++r) linv[r] = 1.f / oaccL[f][r];
#pragma unroll
    for (int d = 0; d < 4; ++d)
#pragma unroll
      for (int r = 0; r < 4; ++r) {
        int sIdx = q0 + f * 16 + fq * 4 + r;
        o[((size_t)(b * Sc + sIdx)) * Ec + h * 64 + d * 16 + fr] =
            f2bf(oacc[f][d][r] * linv[r]);
      }
  }
}

// -----------------------------------------------------------------------------
extern "C" void kernel_launch(void* const* d_in, const int* in_sizes, int n_in,
                              void* d_out, int out_size, void* d_ws, size_t ws_size,
                              hipStream_t stream) {
  const float* inp = (const float*)d_in[0];
  const float* ln1g = (const float*)d_in[1];
  const float* ln1b = (const float*)d_in[2];
  const float* Wq = (const float*)d_in[3];
  const float* bq = (const float*)d_in[4];
  const float* Wk = (const float*)d_in[5];
  const float* bk = (const float*)d_in[6];
  const float* Wv = (const float*)d_in[7];
  const float* bv = (const float*)d_in[8];
  const float* Wo = (const float*)d_in[9];
  const float* bo = (const float*)d_in[10];
  const float* ln2g = (const float*)d_in[11];
  const float* ln2b = (const float*)d_in[12];
  const float* W1 = (const float*)d_in[13];
  const float* b1 = (const float*)d_in[14];
  const float* W2 = (const float*)d_in[15];
  const float* b2 = (const float*)d_in[16];

  char* wsb = (char*)d_ws;
  size_t off = 0;
  auto alloc = [&](size_t bytes) {
    char* p = wsb + off;
    off += (bytes + 255) & ~(size_t)255;
    return p;
  };
  float* xf = (float*)alloc((size_t)Mc * Ec * 4);
  ushort* xb = (ushort*)alloc((size_t)Mc * Ec * 2);
  ushort* qbuf = (ushort*)alloc((size_t)Mc * Ec * 2);
  ushort* kbuf = (ushort*)alloc((size_t)Mc * Ec * 2);
  ushort* vtbuf = (ushort*)alloc((size_t)Mc * Ec * 2);
  ushort* abuf = (ushort*)alloc((size_t)Mc * Ec * 2);
  ushort* h1 = (ushort*)alloc((size_t)Mc * 2 * Ec * 2);
  ushort* WqkvT = (ushort*)alloc((size_t)3 * Ec * Ec * 2);  // [3E][E]
  ushort* WoT = (ushort*)alloc((size_t)Ec * Ec * 2);
  ushort* W1T = (ushort*)alloc((size_t)Ec * 2 * Ec * 2);
  ushort* W2T = (ushort*)alloc((size_t)Ec * 2 * Ec * 2);
  (void)in_sizes; (void)n_in; (void)out_size; (void)ws_size;

  // all 6 weight converts in one launch (8192 blocks)
  wcvt_all_kernel<<<8192, dim3(32, 8), 0, stream>>>(Wq, Wk, Wv, Wo, W1, W2,
                                                    WqkvT, WoT, W1T, W2T);

  ln_kernel<<<Mc, 256, 0, stream>>>(inp, ln1g, ln1b, xf, xb);

  // Fused QKV on the 128² kernel (grid 24x64 = 1536 = 6/CU exact, no tail).
  gemm_kernel<0><<<dim3(3 * Ec / 128, Mc / 128), 256, 0, stream>>>(
      Mc, 3 * Ec, Ec, xb, WqkvT, bq, bk, bv, nullptr, nullptr, qbuf, kbuf,
      vtbuf, 0.18033688f);

  attn_kernel<<<Bc * Hc * (Sc / 128), 256, 0, stream>>>(qbuf, kbuf, vtbuf, abuf);

  gemm_kernel<1><<<dim3(Ec / 128, Mc / 128), 256, 0, stream>>>(
      Mc, Ec, Ec, abuf, WoT, bo, nullptr, nullptr, xf, xf, nullptr, nullptr,
      nullptr, 1.f);

  ln_kernel<<<Mc, 256, 0, stream>>>(xf, ln2g, ln2b, xf, xb);

  // W1 + GELU on the 256² 4-phase kernel (grid 8x32 = 256 = exactly 1/CU)
  gemm256_kernel<2><<<dim3(2 * Ec / 256, Mc / 256), 512, 0, stream>>>(
      Mc, 2 * Ec, Ec, xb, W1T, b1, h1, 1.f);

  gemm_kernel<1><<<dim3(Ec / 128, Mc / 128), 256, 0, stream>>>(
      Mc, Ec, 2 * Ec, h1, W2T, b2, nullptr, nullptr, xf, (float*)d_out,
      nullptr, nullptr, nullptr, 1.f);
}

// Round 16
// 359.678 us; speedup vs baseline: 1.0741x; 1.0149x over previous
//
#include <hip/hip_runtime.h>
#include <hip/hip_bf16.h>

typedef float f32x4 __attribute__((ext_vector_type(4)));
typedef __bf16 bfv8 __attribute__((ext_vector_type(8)));

constexpr int Bc = 4, Sc = 2048, Ec = 1024, Hc = 16, Dc = 64;
constexpr int Mc = Bc * Sc;  // 8192 rows

__device__ __forceinline__ uint pkbf(float lo, float hi) {
  uint r;
  asm("v_cvt_pk_bf16_f32 %0, %1, %2" : "=v"(r) : "v"(lo), "v"(hi));
  return r;
}
__device__ __forceinline__ ushort f2bf(float f) {
  __hip_bfloat16 h = __float2bfloat16(f);
  return __builtin_bit_cast(ushort, h);
}

typedef __attribute__((address_space(1))) unsigned int as1_u32;
typedef __attribute__((address_space(3))) unsigned int as3_u32;
__device__ __forceinline__ void cp16(const ushort* g, ushort* l) {
  // async global->LDS, 16B per lane; LDS dest = wave-uniform base + lane*16
  __builtin_amdgcn_global_load_lds((as1_u32*)g, (as3_u32*)l, 16, 0, 0);
}

// ---------------- all-weights convert+transpose in ONE launch ----------------
// W[K][N] f32 -> WT[N][K] bf16, 32x32 tiles, if-chain block dispatch.
__global__ __launch_bounds__(256) void wcvt_all_kernel(
    const float* __restrict__ Wq, const float* __restrict__ Wk,
    const float* __restrict__ Wv, const float* __restrict__ Wo,
    const float* __restrict__ W1, const float* __restrict__ W2,
    ushort* __restrict__ WqkvT, ushort* __restrict__ WoT,
    ushort* __restrict__ W1T, ushort* __restrict__ W2T) {
  int bid = blockIdx.x;
  const float* W;
  ushort* WT;
  int K, N;
  if (bid < 1024) {
    W = Wq; WT = WqkvT; K = 1024; N = 1024;
  } else if (bid < 2048) {
    W = Wk; WT = WqkvT + (size_t)1024 * 1024; K = 1024; N = 1024; bid -= 1024;
  } else if (bid < 3072) {
    W = Wv; WT = WqkvT + (size_t)2 * 1024 * 1024; K = 1024; N = 1024; bid -= 2048;
  } else if (bid < 4096) {
    W = Wo; WT = WoT; K = 1024; N = 1024; bid -= 3072;
  } else if (bid < 6144) {
    W = W1; WT = W1T; K = 1024; N = 2048; bid -= 4096;
  } else {
    W = W2; WT = W2T; K = 2048; N = 1024; bid -= 6144;
  }
  const int nbx = K / 32;
  const int k0 = (bid % nbx) * 32, n0 = (bid / nbx) * 32;
  __shared__ float t[32][33];
  int tx = threadIdx.x, ty = threadIdx.y;  // (32,8)
#pragma unroll
  for (int i = 0; i < 32; i += 8)
    t[ty + i][tx] = W[(size_t)(k0 + ty + i) * N + n0 + tx];
  __syncthreads();
#pragma unroll
  for (int i = 0; i < 32; i += 8)
    WT[(size_t)(n0 + ty + i) * K + k0 + tx] = f2bf(t[tx][ty + i]);
}

// ---------------- LayerNorm: row of 1024, one block per row ------------------
__global__ __launch_bounds__(256) void ln_kernel(const float* in,
                                                 const float* __restrict__ g,
                                                 const float* __restrict__ bb,
                                                 float* of, ushort* ob) {
  int row = blockIdx.x;
  int t = threadIdx.x;
  float4 x = reinterpret_cast<const float4*>(in + (size_t)row * Ec)[t];
  float s = x.x + x.y + x.z + x.w;
  float q = x.x * x.x + x.y * x.y + x.z * x.z + x.w * x.w;
#pragma unroll
  for (int o = 32; o > 0; o >>= 1) {
    s += __shfl_down(s, o);
    q += __shfl_down(q, o);
  }
  __shared__ float red[10];
  int wv = t >> 6;
  if ((t & 63) == 0) { red[wv] = s; red[4 + wv] = q; }
  __syncthreads();
  if (t == 0) {
    float S = red[0] + red[1] + red[2] + red[3];
    float Q = red[4] + red[5] + red[6] + red[7];
    float mu = S * (1.f / Ec);
    float var = Q * (1.f / Ec) - mu * mu;
    red[8] = mu;
    red[9] = rsqrtf(var + 1e-5f);
  }
  __syncthreads();
  float mu = red[8], rs = red[9];
  float4 gg = reinterpret_cast<const float4*>(g)[t];
  float4 b4 = reinterpret_cast<const float4*>(bb)[t];
  float4 y;
  y.x = (x.x - mu) * rs * gg.x + b4.x;
  y.y = (x.y - mu) * rs * gg.y + b4.y;
  y.z = (x.z - mu) * rs * gg.z + b4.z;
  y.w = (x.w - mu) * rs * gg.w + b4.w;
  reinterpret_cast<float4*>(of + (size_t)row * Ec)[t] = y;
  uint2 u;
  u.x = pkbf(y.x, y.y);
  u.y = pkbf(y.z, y.w);
  reinterpret_cast<uint2*>(ob + (size_t)row * Ec)[t] = u;
}

// ---------------- GEMM 128x128: BK=64, LDS dbuf, counted vmcnt(8) ------------
// Full 3-bit XOR swizzle (slot ^ row&7) on BOTH stage-source and frag-read:
// 2 lanes/slot on ds_read_b128 (was 8-way with the old 2-bit swizzle).
// MODE 0: fused QKV; MODE 1: f32 acc+bias+resid; MODE 2: bf16 gelu(acc+bias)
template <int MODE>
__global__ __launch_bounds__(256, 2) void gemm_kernel(
    int M, int N, int K, const ushort* __restrict__ A,
    const ushort* __restrict__ BT, const float* __restrict__ b0,
    const float* __restrict__ b1, const float* __restrict__ b2,
    const float* resid, float* outF, ushort* o0, ushort* o1, ushort* o2,
    float qscale) {
  __shared__ __align__(16) ushort As[2][128 * 64];
  __shared__ __align__(16) ushort Bs[2][128 * 64];
  const int tid = threadIdx.x;
  const int lane = tid & 63, wave = tid >> 6;
  const int wr = wave >> 1, wc = wave & 1;
  const int fr = lane & 15, fq = lane >> 4;
  const int nx = gridDim.x;
  int flat = blockIdx.x + nx * blockIdx.y;
  int cpx = (nx * gridDim.y) >> 3;
  int work = (flat & 7) * cpx + (flat >> 3);
  const int n0 = (work % nx) * 128, m0 = (work / nx) * 128;

  f32x4 acc[4][4];
#pragma unroll
  for (int i = 0; i < 4; i++)
#pragma unroll
    for (int j = 0; j < 4; j++) acc[i][j] = f32x4{0.f, 0.f, 0.f, 0.f};

  const int srow = tid >> 3;   // 0..31 (+32 per chunk)
  const int sslot = tid & 7;   // 16B slot within 128B row

  auto STAGE = [&](int p, int k0) {
#pragma unroll
    for (int c = 0; c < 4; ++c) {
      int row = c * 32 + srow;
      int scol = (sslot ^ (row & 7)) * 8;  // inverse-swizzled source (3-bit)
      cp16(A + (size_t)(m0 + row) * K + k0 + scol,
           &As[p][(c * 256 + wave * 64) * 8]);
      cp16(BT + (size_t)(n0 + row) * K + k0 + scol,
           &Bs[p][(c * 256 + wave * 64) * 8]);
    }
  };

  STAGE(0, 0);
  const int nt = K >> 6;
  for (int kt = 0; kt < nt; ++kt) {
    const int p = kt & 1;
    if (kt + 1 < nt) {
      STAGE(p ^ 1, (kt + 1) << 6);
      asm volatile("s_waitcnt vmcnt(8)" ::: "memory");  // tile kt landed
    } else {
      asm volatile("s_waitcnt vmcnt(0)" ::: "memory");
    }
    __builtin_amdgcn_s_barrier();
#pragma unroll
    for (int kk = 0; kk < 2; ++kk) {
      bfv8 af[4], bf[4];
#pragma unroll
      for (int m = 0; m < 4; m++) {
        int row = wr * 64 + m * 16 + fr;
        af[m] = *reinterpret_cast<const bfv8*>(
            &As[p][row * 64 + (((kk * 4 + fq) ^ (fr & 7)) * 8)]);
      }
#pragma unroll
      for (int n = 0; n < 4; n++) {
        int row = wc * 64 + n * 16 + fr;
        bf[n] = *reinterpret_cast<const bfv8*>(
            &Bs[p][row * 64 + (((kk * 4 + fq) ^ (fr & 7)) * 8)]);
      }
      __builtin_amdgcn_s_setprio(1);
#pragma unroll
      for (int m = 0; m < 4; m++)
#pragma unroll
        for (int n = 0; n < 4; n++)
          acc[m][n] =
              __builtin_amdgcn_mfma_f32_16x16x32_bf16(af[m], bf[n], acc[m][n], 0, 0, 0);
      __builtin_amdgcn_s_setprio(0);
    }
    __builtin_amdgcn_sched_barrier(0);
    __builtin_amdgcn_s_barrier();
  }

#pragma unroll
  for (int m = 0; m < 4; m++) {
#pragma unroll
    for (int n = 0; n < 4; n++) {
      const int row0 = m0 + wr * 64 + m * 16 + fq * 4;
      const int col = n0 + wc * 64 + n * 16 + fr;
      if constexpr (MODE == 0) {
        const int region = col >> 10, c1 = col & (Ec - 1);
        const int b = row0 >> 11, s0 = row0 & (Sc - 1);
        const int h = c1 >> 6, d = c1 & (Dc - 1);
        const float bb = (region == 0 ? b0 : region == 1 ? b1 : b2)[c1];
        if (region == 2) {
          uint2 u;
          u.x = pkbf(acc[m][n][0] + bb, acc[m][n][1] + bb);
          u.y = pkbf(acc[m][n][2] + bb, acc[m][n][3] + bb);
          *reinterpret_cast<uint2*>(
              &o2[(((size_t)b * Hc + h) * Dc + d) * Sc + s0]) = u;
        } else {
          ushort* dst = region ? o1 : o0;
          const float sc = region ? 1.f : qscale;
#pragma unroll
          for (int r = 0; r < 4; r++)
            dst[(((size_t)b * Hc + h) * Sc + s0 + r) * Dc + d] =
                f2bf((acc[m][n][r] + bb) * sc);
        }
      } else {
        const float bb = b0[col];
#pragma unroll
        for (int r = 0; r < 4; r++) {
          int row = row0 + r;
          float vacc = acc[m][n][r] + bb;
          if constexpr (MODE == 1) {
            size_t idx = (size_t)row * N + col;
            outF[idx] = vacc + resid[idx];
          } else {
            vacc = 0.5f * vacc * (1.f + erff(vacc * 0.70710678118f));
            o0[(size_t)row * N + col] = f2bf(vacc);
          }
        }
      }
    }
  }
}

// ======== 256x256 8-wave 4-phase GEMM (W1 only: grid 256 = exactly 1/CU) ====
// MODE 2: bf16 gelu(acc+bias)
template <int MODE>
__global__ __launch_bounds__(512, 2) void gemm256_kernel(
    int M, int N, int K, const ushort* __restrict__ A,
    const ushort* __restrict__ BT, const float* __restrict__ b0,
    ushort* o0, float qscale) {
  __shared__ __align__(16) ushort As[2][256 * 64];
  __shared__ __align__(16) ushort Bs[2][256 * 64];
  const int tid = threadIdx.x;
  const int lane = tid & 63, wave = tid >> 6;  // 8 waves
  const int wr = wave >> 2, wc = wave & 3;     // 2 x 4
  const int fr = lane & 15, fq = lane >> 4;
  const int nx = gridDim.x;
  int flat = blockIdx.x + nx * blockIdx.y;
  int cpx = (nx * gridDim.y) >> 3;
  int work = (flat & 7) * cpx + (flat >> 3);
  const int n0 = (work % nx) * 256, m0 = (work / nx) * 256;

  f32x4 acc[8][4];
#pragma unroll
  for (int i = 0; i < 8; i++)
#pragma unroll
    for (int j = 0; j < 4; j++) acc[i][j] = f32x4{0.f, 0.f, 0.f, 0.f};

  const int srow = tid >> 3;  // 0..63
  const int sslot = tid & 7;

  auto STAGE = [&](int p, int k0) {
#pragma unroll
    for (int c = 0; c < 4; ++c) {
      int row = c * 64 + srow;
      int scol = (sslot ^ (row & 7)) * 8;  // inverse-swizzled source
      cp16(A + (size_t)(m0 + row) * K + k0 + scol,
           &As[p][(c * 64 + wave * 8) * 64]);
      cp16(BT + (size_t)(n0 + row) * K + k0 + scol,
           &Bs[p][(c * 64 + wave * 8) * 64]);
    }
  };

  STAGE(0, 0);
  const int nt = K >> 6;
  for (int kt = 0; kt < nt; ++kt) {
    const int p = kt & 1;
    if (kt + 1 < nt) {
      STAGE(p ^ 1, (kt + 1) << 6);
      asm volatile("s_waitcnt vmcnt(8)" ::: "memory");  // tile kt landed
    } else {
      asm volatile("s_waitcnt vmcnt(0)" ::: "memory");
    }
    __builtin_amdgcn_s_barrier();
#pragma unroll
    for (int kk = 0; kk < 2; ++kk) {
      bfv8 bfr[4];
#pragma unroll
      for (int n = 0; n < 4; ++n) {
        int row = wc * 64 + n * 16 + fr;
        bfr[n] = *reinterpret_cast<const bfv8*>(
            &Bs[p][row * 64 + (((kk * 4 + fq) ^ (row & 7)) * 8)]);
      }
#pragma unroll
      for (int mh = 0; mh < 2; ++mh) {
        bfv8 af[4];
#pragma unroll
        for (int mm = 0; mm < 4; ++mm) {
          int row = wr * 128 + (mh * 4 + mm) * 16 + fr;
          af[mm] = *reinterpret_cast<const bfv8*>(
              &As[p][row * 64 + (((kk * 4 + fq) ^ (row & 7)) * 8)]);
        }
        __builtin_amdgcn_s_setprio(1);
#pragma unroll
        for (int mm = 0; mm < 4; ++mm)
#pragma unroll
          for (int n = 0; n < 4; ++n)
            acc[mh * 4 + mm][n] = __builtin_amdgcn_mfma_f32_16x16x32_bf16(
                af[mm], bfr[n], acc[mh * 4 + mm][n], 0, 0, 0);
        __builtin_amdgcn_s_setprio(0);
        if (!(kk == 1 && mh == 1)) __builtin_amdgcn_s_barrier();  // phase edge
      }
    }
    __builtin_amdgcn_sched_barrier(0);
    __builtin_amdgcn_s_barrier();  // tile edge: all reads of buf p done
  }

#pragma unroll
  for (int m = 0; m < 8; m++) {
#pragma unroll
    for (int n = 0; n < 4; n++) {
      const int row0 = m0 + wr * 128 + m * 16 + fq * 4;
      const int col = n0 + wc * 64 + n * 16 + fr;
      const float bb = b0[col];
#pragma unroll
      for (int r = 0; r < 4; r++) {
        float vacc = acc[m][n][r] + bb;
        vacc = 0.5f * vacc * (1.f + erff(vacc * 0.70710678118f));
        o0[(size_t)(row0 + r) * N + col] = f2bf(vacc);
      }
    }
  }
}

// ---------------- Flash attention (32 q-rows per wave, 128 per block) --------
// R13-exact (known good): K/V LDS double-buffered, counted vmcnt(4) + raw
// barriers; l-sum via ones-MFMA; pad-free XOR-swizzled Ps. LDS 40960 B.
__global__ __launch_bounds__(256) void attn_kernel(const ushort* __restrict__ q,
                                                   const ushort* __restrict__ k,
                                                   const ushort* __restrict__ vt,
                                                   ushort* __restrict__ o) {
  int flat = blockIdx.x;                     // 1024 blocks
  int swz = (flat & 7) * 128 + (flat >> 3);  // XCD-chunked: 8 heads per XCD
  const int qb = swz & 15;                   // 16 q-blocks of 128 rows
  const int bh = swz >> 4;
  const int tid = threadIdx.x, lane = tid & 63, wave = tid >> 6;
  const int fr = lane & 15, fq = lane >> 4;
  const size_t base = (size_t)bh * Sc * Dc;
  const int q0 = qb * 128 + wave * 32;

  __shared__ __align__(16) ushort Ks[2][64 * 64];  // [key][d], XOR-swizzled
  __shared__ __align__(16) ushort Vt[2][64 * 64];  // [d][key], XOR-swizzled
  __shared__ __align__(16) ushort Ps[4][16 * 64];  // per-wave P, XOR-swizzled

  bfv8 qf0[2], qf1[2];
#pragma unroll
  for (int f = 0; f < 2; ++f) {
    const ushort* qp = q + base + (size_t)(q0 + f * 16 + fr) * Dc + fq * 8;
    qf0[f] = *reinterpret_cast<const bfv8*>(qp);
    qf1[f] = *reinterpret_cast<const bfv8*>(qp + 32);
  }

  const bfv8 ones = __builtin_bit_cast(bfv8, uint4{0x3F803F80u, 0x3F803F80u,
                                                  0x3F803F80u, 0x3F803F80u});

  f32x4 oacc[2][4];  // [frag][dtile]
  f32x4 oaccL[2];    // row-sum accumulator (l)
#pragma unroll
  for (int f = 0; f < 2; ++f) {
    oaccL[f] = f32x4{0.f, 0.f, 0.f, 0.f};
#pragma unroll
    for (int d = 0; d < 4; ++d) oacc[f][d] = f32x4{0.f, 0.f, 0.f, 0.f};
  }
  float mrow[2] = {-3e38f, -3e38f};

  const int r8 = tid >> 3;  // staging row 0..31
  const int c8 = tid & 7;   // staging 16B chunk

  auto STAGE = [&](int p, int key0) {
#pragma unroll
    for (int i = 0; i < 2; ++i) {
      int row = i * 32 + r8;
      int sc = (c8 ^ (row & 7)) * 8;  // inverse-swizzled source
      cp16(k + base + (size_t)(key0 + row) * Dc + sc,
           &Ks[p][i * 2048 + wave * 512]);
      cp16(vt + base + (size_t)row * Sc + key0 + sc,
           &Vt[p][i * 2048 + wave * 512]);
    }
  };

  const int sA = (fq ^ (fr & 7)) * 8;
  const int sB = ((fq + 4) ^ (fr & 7)) * 8;

  const int pswz = 2 * (fr & 7);
  const int pr0 = fr * 64 + ((fq * 2) ^ pswz) * 4;
  const int pr1 = fr * 64 + ((fq * 2 + 8) ^ pswz) * 4;

  STAGE(0, 0);
  constexpr int NT = Sc / 64;
  for (int kt = 0; kt < NT; ++kt) {
    const int p = kt & 1;
    if (kt + 1 < NT) {
      STAGE(p ^ 1, (kt + 1) * 64);
      asm volatile("s_waitcnt vmcnt(4)" ::: "memory");
    } else {
      asm volatile("s_waitcnt vmcnt(0)" ::: "memory");
    }
    __builtin_amdgcn_s_barrier();

    bfv8 kf0[4], kf1[4], vf0[4], vf1[4];
#pragma unroll
    for (int t = 0; t < 4; ++t) {
      int e = (t * 16 + fr) * 64;
      kf0[t] = *reinterpret_cast<const bfv8*>(&Ks[p][e + sA]);
      kf1[t] = *reinterpret_cast<const bfv8*>(&Ks[p][e + sB]);
      vf0[t] = *reinterpret_cast<const bfv8*>(&Vt[p][e + sA]);
      vf1[t] = *reinterpret_cast<const bfv8*>(&Vt[p][e + sB]);
    }

#pragma unroll
    for (int f = 0; f < 2; ++f) {
      f32x4 sf[4];
      __builtin_amdgcn_s_setprio(1);
#pragma unroll
      for (int t = 0; t < 4; ++t) {
        sf[t] = f32x4{0.f, 0.f, 0.f, 0.f};
        sf[t] = __builtin_amdgcn_mfma_f32_16x16x32_bf16(kf0[t], qf0[f], sf[t], 0, 0, 0);
        sf[t] = __builtin_amdgcn_mfma_f32_16x16x32_bf16(kf1[t], qf1[f], sf[t], 0, 0, 0);
      }
      __builtin_amdgcn_s_setprio(0);
      float mt0 = fmaxf(fmaxf(sf[0][0], sf[0][1]), fmaxf(sf[0][2], sf[0][3]));
      float mt1 = fmaxf(fmaxf(sf[1][0], sf[1][1]), fmaxf(sf[1][2], sf[1][3]));
      float mt2 = fmaxf(fmaxf(sf[2][0], sf[2][1]), fmaxf(sf[2][2], sf[2][3]));
      float mt3 = fmaxf(fmaxf(sf[3][0], sf[3][1]), fmaxf(sf[3][2], sf[3][3]));
      float pmax = fmaxf(fmaxf(mt0, mt1), fmaxf(mt2, mt3));
      float m = mrow[f];
      float mnew = m;
      if (!__all(pmax <= m + 8.f)) {
        float mt = fmaxf(pmax, __shfl_xor(pmax, 16));
        mt = fmaxf(mt, __shfl_xor(mt, 32));
        mnew = fmaxf(m, mt);
        float alpha = __builtin_amdgcn_exp2f(m - mnew);
        float ar[4];
#pragma unroll
        for (int r = 0; r < 4; ++r) ar[r] = __shfl(alpha, fq * 4 + r);
#pragma unroll
        for (int d = 0; d < 4; ++d)
#pragma unroll
          for (int r = 0; r < 4; ++r) oacc[f][d][r] *= ar[r];
#pragma unroll
        for (int r = 0; r < 4; ++r) oaccL[f][r] *= ar[r];
        mrow[f] = mnew;
      }
      ushort* pw = &Ps[wave][0];
#pragma unroll
      for (int t = 0; t < 4; ++t) {
        uint2 pu;
        pu.x = pkbf(__builtin_amdgcn_exp2f(sf[t][0] - mnew),
                    __builtin_amdgcn_exp2f(sf[t][1] - mnew));
        pu.y = pkbf(__builtin_amdgcn_exp2f(sf[t][2] - mnew),
                    __builtin_amdgcn_exp2f(sf[t][3] - mnew));
        int us = fr * 64 + ((t * 4 + fq) ^ pswz) * 4;
        *reinterpret_cast<uint2*>(&pw[us]) = pu;
      }
      bfv8 pf0 = *reinterpret_cast<const bfv8*>(&pw[pr0]);
      bfv8 pf1 = *reinterpret_cast<const bfv8*>(&pw[pr1]);
      __builtin_amdgcn_s_setprio(1);
#pragma unroll
      for (int d = 0; d < 4; ++d) {
        oacc[f][d] = __builtin_amdgcn_mfma_f32_16x16x32_bf16(pf0, vf0[d], oacc[f][d], 0, 0, 0);
        oacc[f][d] = __builtin_amdgcn_mfma_f32_16x16x32_bf16(pf1, vf1[d], oacc[f][d], 0, 0, 0);
      }
      oaccL[f] = __builtin_amdgcn_mfma_f32_16x16x32_bf16(pf0, ones, oaccL[f], 0, 0, 0);
      oaccL[f] = __builtin_amdgcn_mfma_f32_16x16x32_bf16(pf1, ones, oaccL[f], 0, 0, 0);
      __builtin_amdgcn_s_setprio(0);
    }
    __builtin_amdgcn_sched_barrier(0);
    __builtin_amdgcn_s_barrier();
  }

  const int b = bh >> 4, h = bh & 15;
#pragma unroll
  for (int f = 0; f < 2; ++f) {
    float linv[4];
#pragma unroll
    for (int r = 0; r < 4; ++r) linv[r] = 1.f / oaccL[f][r];
#pragma unroll
    for (int d = 0; d < 4; ++d)
#pragma unroll
      for (int r = 0; r < 4; ++r) {
        int sIdx = q0 + f * 16 + fq * 4 + r;
        o[((size_t)(b * Sc + sIdx)) * Ec + h * 64 + d * 16 + fr] =
            f2bf(oacc[f][d][r] * linv[r]);
      }
  }
}

// -----------------------------------------------------------------------------
extern "C" void kernel_launch(void* const* d_in, const int* in_sizes, int n_in,
                              void* d_out, int out_size, void* d_ws, size_t ws_size,
                              hipStream_t stream) {
  const float* inp = (const float*)d_in[0];
  const float* ln1g = (const float*)d_in[1];
  const float* ln1b = (const float*)d_in[2];
  const float* Wq = (const float*)d_in[3];
  const float* bq = (const float*)d_in[4];
  const float* Wk = (const float*)d_in[5];
  const float* bk = (const float*)d_in[6];
  const float* Wv = (const float*)d_in[7];
  const float* bv = (const float*)d_in[8];
  const float* Wo = (const float*)d_in[9];
  const float* bo = (const float*)d_in[10];
  const float* ln2g = (const float*)d_in[11];
  const float* ln2b = (const float*)d_in[12];
  const float* W1 = (const float*)d_in[13];
  const float* b1 = (const float*)d_in[14];
  const float* W2 = (const float*)d_in[15];
  const float* b2 = (const float*)d_in[16];

  char* wsb = (char*)d_ws;
  size_t off = 0;
  auto alloc = [&](size_t bytes) {
    char* p = wsb + off;
    off += (bytes + 255) & ~(size_t)255;
    return p;
  };
  float* xf = (float*)alloc((size_t)Mc * Ec * 4);
  ushort* xb = (ushort*)alloc((size_t)Mc * Ec * 2);
  ushort* qbuf = (ushort*)alloc((size_t)Mc * Ec * 2);
  ushort* kbuf = (ushort*)alloc((size_t)Mc * Ec * 2);
  ushort* vtbuf = (ushort*)alloc((size_t)Mc * Ec * 2);
  ushort* abuf = (ushort*)alloc((size_t)Mc * Ec * 2);
  ushort* h1 = (ushort*)alloc((size_t)Mc * 2 * Ec * 2);
  ushort* WqkvT = (ushort*)alloc((size_t)3 * Ec * Ec * 2);  // [3E][E]
  ushort* WoT = (ushort*)alloc((size_t)Ec * Ec * 2);
  ushort* W1T = (ushort*)alloc((size_t)Ec * 2 * Ec * 2);
  ushort* W2T = (ushort*)alloc((size_t)Ec * 2 * Ec * 2);
  (void)in_sizes; (void)n_in; (void)out_size; (void)ws_size;

  // all 6 weight converts in one launch (8192 blocks)
  wcvt_all_kernel<<<8192, dim3(32, 8), 0, stream>>>(Wq, Wk, Wv, Wo, W1, W2,
                                                    WqkvT, WoT, W1T, W2T);

  ln_kernel<<<Mc, 256, 0, stream>>>(inp, ln1g, ln1b, xf, xb);

  // Fused QKV on the 128² kernel (grid 24x64 = 1536 = 6/CU exact, no tail).
  gemm_kernel<0><<<dim3(3 * Ec / 128, Mc / 128), 256, 0, stream>>>(
      Mc, 3 * Ec, Ec, xb, WqkvT, bq, bk, bv, nullptr, nullptr, qbuf, kbuf,
      vtbuf, 0.18033688f);

  attn_kernel<<<Bc * Hc * (Sc / 128), 256, 0, stream>>>(qbuf, kbuf, vtbuf, abuf);

  gemm_kernel<1><<<dim3(Ec / 128, Mc / 128), 256, 0, stream>>>(
      Mc, Ec, Ec, abuf, WoT, bo, nullptr, nullptr, xf, xf, nullptr, nullptr,
      nullptr, 1.f);

  ln_kernel<<<Mc, 256, 0, stream>>>(xf, ln2g, ln2b, xf, xb);

  // W1 + GELU on the 256² 4-phase kernel (grid 8x32 = 256 = exactly 1/CU)
  gemm256_kernel<2><<<dim3(2 * Ec / 256, Mc / 256), 512, 0, stream>>>(
      Mc, 2 * Ec, Ec, xb, W1T, b1, h1, 1.f);

  gemm_kernel<1><<<dim3(Ec / 128, Mc / 128), 256, 0, stream>>>(
      Mc, Ec, 2 * Ec, h1, W2T, b2, nullptr, nullptr, xf, (float*)d_out,
      nullptr, nullptr, nullptr, 1.f);
}

// Round 17
// 333.532 us; speedup vs baseline: 1.1583x; 1.0784x over previous
//
#include <hip/hip_runtime.h>
#include <hip/hip_bf16.h>

typedef float f32x4 __attribute__((ext_vector_type(4)));
typedef __bf16 bfv8 __attribute__((ext_vector_type(8)));

constexpr int Bc = 4, Sc = 2048, Ec = 1024, Hc = 16, Dc = 64;
constexpr int Mc = Bc * Sc;  // 8192 rows

__device__ __forceinline__ uint pkbf(float lo, float hi) {
  uint r;
  asm("v_cvt_pk_bf16_f32 %0, %1, %2" : "=v"(r) : "v"(lo), "v"(hi));
  return r;
}
__device__ __forceinline__ ushort f2bf(float f) {
  __hip_bfloat16 h = __float2bfloat16(f);
  return __builtin_bit_cast(ushort, h);
}
__device__ __forceinline__ float bf2f(ushort u) {
  return __builtin_bit_cast(float, (uint)u << 16);
}

typedef __attribute__((address_space(1))) unsigned int as1_u32;
typedef __attribute__((address_space(3))) unsigned int as3_u32;
__device__ __forceinline__ void cp16(const ushort* g, ushort* l) {
  // async global->LDS, 16B per lane; LDS dest = wave-uniform base + lane*16
  __builtin_amdgcn_global_load_lds((as1_u32*)g, (as3_u32*)l, 16, 0, 0);
}

// ---------------- all-weights convert+transpose in ONE launch ----------------
// W[K][N] f32 -> WT[N][K] bf16, 32x32 tiles, if-chain block dispatch.
__global__ __launch_bounds__(256) void wcvt_all_kernel(
    const float* __restrict__ Wq, const float* __restrict__ Wk,
    const float* __restrict__ Wv, const float* __restrict__ Wo,
    const float* __restrict__ W1, const float* __restrict__ W2,
    ushort* __restrict__ WqkvT, ushort* __restrict__ WoT,
    ushort* __restrict__ W1T, ushort* __restrict__ W2T) {
  int bid = blockIdx.x;
  const float* W;
  ushort* WT;
  int K, N;
  if (bid < 1024) {
    W = Wq; WT = WqkvT; K = 1024; N = 1024;
  } else if (bid < 2048) {
    W = Wk; WT = WqkvT + (size_t)1024 * 1024; K = 1024; N = 1024; bid -= 1024;
  } else if (bid < 3072) {
    W = Wv; WT = WqkvT + (size_t)2 * 1024 * 1024; K = 1024; N = 1024; bid -= 2048;
  } else if (bid < 4096) {
    W = Wo; WT = WoT; K = 1024; N = 1024; bid -= 3072;
  } else if (bid < 6144) {
    W = W1; WT = W1T; K = 1024; N = 2048; bid -= 4096;
  } else {
    W = W2; WT = W2T; K = 2048; N = 1024; bid -= 6144;
  }
  const int nbx = K / 32;
  const int k0 = (bid % nbx) * 32, n0 = (bid / nbx) * 32;
  __shared__ float t[32][33];
  int tx = threadIdx.x, ty = threadIdx.y;  // (32,8)
#pragma unroll
  for (int i = 0; i < 32; i += 8)
    t[ty + i][tx] = W[(size_t)(k0 + ty + i) * N + n0 + tx];
  __syncthreads();
#pragma unroll
  for (int i = 0; i < 32; i += 8)
    WT[(size_t)(n0 + ty + i) * K + k0 + tx] = f2bf(t[tx][ty + i]);
}

// ---------------- LayerNorm: row of 1024, one block per row ------------------
// INF32=1: f32 input; INF32=0: bf16 input. Output bf16 only.
template <int INF32>
__global__ __launch_bounds__(256) void ln_kernel(const void* in,
                                                 const float* __restrict__ g,
                                                 const float* __restrict__ bb,
                                                 ushort* ob) {
  int row = blockIdx.x;
  int t = threadIdx.x;
  float4 x;
  if constexpr (INF32) {
    x = reinterpret_cast<const float4*>((const float*)in + (size_t)row * Ec)[t];
  } else {
    uint2 u = reinterpret_cast<const uint2*>((const ushort*)in + (size_t)row * Ec)[t];
    x.x = __builtin_bit_cast(float, u.x << 16);
    x.y = __builtin_bit_cast(float, u.x & 0xFFFF0000u);
    x.z = __builtin_bit_cast(float, u.y << 16);
    x.w = __builtin_bit_cast(float, u.y & 0xFFFF0000u);
  }
  float s = x.x + x.y + x.z + x.w;
  float q = x.x * x.x + x.y * x.y + x.z * x.z + x.w * x.w;
#pragma unroll
  for (int o = 32; o > 0; o >>= 1) {
    s += __shfl_down(s, o);
    q += __shfl_down(q, o);
  }
  __shared__ float red[10];
  int wv = t >> 6;
  if ((t & 63) == 0) { red[wv] = s; red[4 + wv] = q; }
  __syncthreads();
  if (t == 0) {
    float S = red[0] + red[1] + red[2] + red[3];
    float Q = red[4] + red[5] + red[6] + red[7];
    float mu = S * (1.f / Ec);
    float var = Q * (1.f / Ec) - mu * mu;
    red[8] = mu;
    red[9] = rsqrtf(var + 1e-5f);
  }
  __syncthreads();
  float mu = red[8], rs = red[9];
  float4 gg = reinterpret_cast<const float4*>(g)[t];
  float4 b4 = reinterpret_cast<const float4*>(bb)[t];
  float4 y;
  y.x = (x.x - mu) * rs * gg.x + b4.x;
  y.y = (x.y - mu) * rs * gg.y + b4.y;
  y.z = (x.z - mu) * rs * gg.z + b4.z;
  y.w = (x.w - mu) * rs * gg.w + b4.w;
  uint2 u;
  u.x = pkbf(y.x, y.y);
  u.y = pkbf(y.z, y.w);
  reinterpret_cast<uint2*>(ob + (size_t)row * Ec)[t] = u;
}

// ---------------- GEMM 128x128: BK=64, LDS dbuf, counted vmcnt(8) ------------
// Full 3-bit XOR swizzle on BOTH stage-source and frag-read.
// MODE 0: fused QKV -> Q,K [B,H,S,D] + V^T [B,H,D,S] (bf16)
// MODE 1: bf16 out = acc + bias + bf16 resid (Wo)
// MODE 3: f32 out = acc + bias + bf16 resid (final W2)
template <int MODE>
__global__ __launch_bounds__(256, 2) void gemm_kernel(
    int M, int N, int K, const ushort* __restrict__ A,
    const ushort* __restrict__ BT, const float* __restrict__ b0,
    const float* __restrict__ b1, const float* __restrict__ b2,
    const ushort* __restrict__ rb, float* outF, ushort* o0, ushort* o1,
    ushort* o2, float qscale) {
  __shared__ __align__(16) ushort As[2][128 * 64];
  __shared__ __align__(16) ushort Bs[2][128 * 64];
  const int tid = threadIdx.x;
  const int lane = tid & 63, wave = tid >> 6;
  const int wr = wave >> 1, wc = wave & 1;
  const int fr = lane & 15, fq = lane >> 4;
  const int nx = gridDim.x;
  int flat = blockIdx.x + nx * blockIdx.y;
  int cpx = (nx * gridDim.y) >> 3;
  int work = (flat & 7) * cpx + (flat >> 3);
  const int n0 = (work % nx) * 128, m0 = (work / nx) * 128;

  f32x4 acc[4][4];
#pragma unroll
  for (int i = 0; i < 4; i++)
#pragma unroll
    for (int j = 0; j < 4; j++) acc[i][j] = f32x4{0.f, 0.f, 0.f, 0.f};

  const int srow = tid >> 3;   // 0..31 (+32 per chunk)
  const int sslot = tid & 7;   // 16B slot within 128B row

  auto STAGE = [&](int p, int k0) {
#pragma unroll
    for (int c = 0; c < 4; ++c) {
      int row = c * 32 + srow;
      int scol = (sslot ^ (row & 7)) * 8;  // inverse-swizzled source (3-bit)
      cp16(A + (size_t)(m0 + row) * K + k0 + scol,
           &As[p][(c * 256 + wave * 64) * 8]);
      cp16(BT + (size_t)(n0 + row) * K + k0 + scol,
           &Bs[p][(c * 256 + wave * 64) * 8]);
    }
  };

  STAGE(0, 0);
  const int nt = K >> 6;
  for (int kt = 0; kt < nt; ++kt) {
    const int p = kt & 1;
    if (kt + 1 < nt) {
      STAGE(p ^ 1, (kt + 1) << 6);
      asm volatile("s_waitcnt vmcnt(8)" ::: "memory");  // tile kt landed
    } else {
      asm volatile("s_waitcnt vmcnt(0)" ::: "memory");
    }
    __builtin_amdgcn_s_barrier();
#pragma unroll
    for (int kk = 0; kk < 2; ++kk) {
      bfv8 af[4], bf[4];
#pragma unroll
      for (int m = 0; m < 4; m++) {
        int row = wr * 64 + m * 16 + fr;
        af[m] = *reinterpret_cast<const bfv8*>(
            &As[p][row * 64 + (((kk * 4 + fq) ^ (fr & 7)) * 8)]);
      }
#pragma unroll
      for (int n = 0; n < 4; n++) {
        int row = wc * 64 + n * 16 + fr;
        bf[n] = *reinterpret_cast<const bfv8*>(
            &Bs[p][row * 64 + (((kk * 4 + fq) ^ (fr & 7)) * 8)]);
      }
      __builtin_amdgcn_s_setprio(1);
#pragma unroll
      for (int m = 0; m < 4; m++)
#pragma unroll
        for (int n = 0; n < 4; n++)
          acc[m][n] =
              __builtin_amdgcn_mfma_f32_16x16x32_bf16(af[m], bf[n], acc[m][n], 0, 0, 0);
      __builtin_amdgcn_s_setprio(0);
    }
    __builtin_amdgcn_sched_barrier(0);
    __builtin_amdgcn_s_barrier();
  }

#pragma unroll
  for (int m = 0; m < 4; m++) {
#pragma unroll
    for (int n = 0; n < 4; n++) {
      const int row0 = m0 + wr * 64 + m * 16 + fq * 4;
      const int col = n0 + wc * 64 + n * 16 + fr;
      if constexpr (MODE == 0) {
        const int region = col >> 10, c1 = col & (Ec - 1);
        const int b = row0 >> 11, s0 = row0 & (Sc - 1);
        const int h = c1 >> 6, d = c1 & (Dc - 1);
        const float bb = (region == 0 ? b0 : region == 1 ? b1 : b2)[c1];
        if (region == 2) {
          uint2 u;
          u.x = pkbf(acc[m][n][0] + bb, acc[m][n][1] + bb);
          u.y = pkbf(acc[m][n][2] + bb, acc[m][n][3] + bb);
          *reinterpret_cast<uint2*>(
              &o2[(((size_t)b * Hc + h) * Dc + d) * Sc + s0]) = u;
        } else {
          ushort* dst = region ? o1 : o0;
          const float sc = region ? 1.f : qscale;
#pragma unroll
          for (int r = 0; r < 4; r++)
            dst[(((size_t)b * Hc + h) * Sc + s0 + r) * Dc + d] =
                f2bf((acc[m][n][r] + bb) * sc);
        }
      } else {
        const float bb = b0[col];
#pragma unroll
        for (int r = 0; r < 4; r++) {
          int row = row0 + r;
          size_t idx = (size_t)row * N + col;
          float vacc = acc[m][n][r] + bb + bf2f(rb[idx]);
          if constexpr (MODE == 1) {
            o0[idx] = f2bf(vacc);
          } else {
            outF[idx] = vacc;
          }
        }
      }
    }
  }
}

// ======== 256x256 8-wave 4-phase GEMM (W1 only: grid 256 = exactly 1/CU) ====
// MODE 2: bf16 gelu(acc+bias)
template <int MODE>
__global__ __launch_bounds__(512, 2) void gemm256_kernel(
    int M, int N, int K, const ushort* __restrict__ A,
    const ushort* __restrict__ BT, const float* __restrict__ b0,
    ushort* o0, float qscale) {
  __shared__ __align__(16) ushort As[2][256 * 64];
  __shared__ __align__(16) ushort Bs[2][256 * 64];
  const int tid = threadIdx.x;
  const int lane = tid & 63, wave = tid >> 6;  // 8 waves
  const int wr = wave >> 2, wc = wave & 3;     // 2 x 4
  const int fr = lane & 15, fq = lane >> 4;
  const int nx = gridDim.x;
  int flat = blockIdx.x + nx * blockIdx.y;
  int cpx = (nx * gridDim.y) >> 3;
  int work = (flat & 7) * cpx + (flat >> 3);
  const int n0 = (work % nx) * 256, m0 = (work / nx) * 256;

  f32x4 acc[8][4];
#pragma unroll
  for (int i = 0; i < 8; i++)
#pragma unroll
    for (int j = 0; j < 4; j++) acc[i][j] = f32x4{0.f, 0.f, 0.f, 0.f};

  const int srow = tid >> 3;  // 0..63
  const int sslot = tid & 7;

  auto STAGE = [&](int p, int k0) {
#pragma unroll
    for (int c = 0; c < 4; ++c) {
      int row = c * 64 + srow;
      int scol = (sslot ^ (row & 7)) * 8;  // inverse-swizzled source
      cp16(A + (size_t)(m0 + row) * K + k0 + scol,
           &As[p][(c * 64 + wave * 8) * 64]);
      cp16(BT + (size_t)(n0 + row) * K + k0 + scol,
           &Bs[p][(c * 64 + wave * 8) * 64]);
    }
  };

  STAGE(0, 0);
  const int nt = K >> 6;
  for (int kt = 0; kt < nt; ++kt) {
    const int p = kt & 1;
    if (kt + 1 < nt) {
      STAGE(p ^ 1, (kt + 1) << 6);
      asm volatile("s_waitcnt vmcnt(8)" ::: "memory");  // tile kt landed
    } else {
      asm volatile("s_waitcnt vmcnt(0)" ::: "memory");
    }
    __builtin_amdgcn_s_barrier();
#pragma unroll
    for (int kk = 0; kk < 2; ++kk) {
      bfv8 bfr[4];
#pragma unroll
      for (int n = 0; n < 4; ++n) {
        int row = wc * 64 + n * 16 + fr;
        bfr[n] = *reinterpret_cast<const bfv8*>(
            &Bs[p][row * 64 + (((kk * 4 + fq) ^ (row & 7)) * 8)]);
      }
#pragma unroll
      for (int mh = 0; mh < 2; ++mh) {
        bfv8 af[4];
#pragma unroll
        for (int mm = 0; mm < 4; ++mm) {
          int row = wr * 128 + (mh * 4 + mm) * 16 + fr;
          af[mm] = *reinterpret_cast<const bfv8*>(
              &As[p][row * 64 + (((kk * 4 + fq) ^ (row & 7)) * 8)]);
        }
        __builtin_amdgcn_s_setprio(1);
#pragma unroll
        for (int mm = 0; mm < 4; ++mm)
#pragma unroll
          for (int n = 0; n < 4; ++n)
            acc[mh * 4 + mm][n] = __builtin_amdgcn_mfma_f32_16x16x32_bf16(
                af[mm], bfr[n], acc[mh * 4 + mm][n], 0, 0, 0);
        __builtin_amdgcn_s_setprio(0);
        if (!(kk == 1 && mh == 1)) __builtin_amdgcn_s_barrier();  // phase edge
      }
    }
    __builtin_amdgcn_sched_barrier(0);
    __builtin_amdgcn_s_barrier();  // tile edge: all reads of buf p done
  }

#pragma unroll
  for (int m = 0; m < 8; m++) {
#pragma unroll
    for (int n = 0; n < 4; n++) {
      const int row0 = m0 + wr * 128 + m * 16 + fq * 4;
      const int col = n0 + wc * 64 + n * 16 + fr;
      const float bb = b0[col];
#pragma unroll
      for (int r = 0; r < 4; r++) {
        float vacc = acc[m][n][r] + bb;
        vacc = 0.5f * vacc * (1.f + erff(vacc * 0.70710678118f));
        o0[(size_t)(row0 + r) * N + col] = f2bf(vacc);
      }
    }
  }
}

// ---------------- Flash attention (32 q-rows per wave, 128 per block) --------
// R13-exact (known good): K/V LDS double-buffered, counted vmcnt(4) + raw
// barriers; l-sum via ones-MFMA; pad-free XOR-swizzled Ps. LDS 40960 B.
__global__ __launch_bounds__(256) void attn_kernel(const ushort* __restrict__ q,
                                                   const ushort* __restrict__ k,
                                                   const ushort* __restrict__ vt,
                                                   ushort* __restrict__ o) {
  int flat = blockIdx.x;                     // 1024 blocks
  int swz = (flat & 7) * 128 + (flat >> 3);  // XCD-chunked: 8 heads per XCD
  const int qb = swz & 15;                   // 16 q-blocks of 128 rows
  const int bh = swz >> 4;
  const int tid = threadIdx.x, lane = tid & 63, wave = tid >> 6;
  const int fr = lane & 15, fq = lane >> 4;
  const size_t base = (size_t)bh * Sc * Dc;
  const int q0 = qb * 128 + wave * 32;

  __shared__ __align__(16) ushort Ks[2][64 * 64];  // [key][d], XOR-swizzled
  __shared__ __align__(16) ushort Vt[2][64 * 64];  // [d][key], XOR-swizzled
  __shared__ __align__(16) ushort Ps[4][16 * 64];  // per-wave P, XOR-swizzled

  bfv8 qf0[2], qf1[2];
#pragma unroll
  for (int f = 0; f < 2; ++f) {
    const ushort* qp = q + base + (size_t)(q0 + f * 16 + fr) * Dc + fq * 8;
    qf0[f] = *reinterpret_cast<const bfv8*>(qp);
    qf1[f] = *reinterpret_cast<const bfv8*>(qp + 32);
  }

  const bfv8 ones = __builtin_bit_cast(bfv8, uint4{0x3F803F80u, 0x3F803F80u,
                                                  0x3F803F80u, 0x3F803F80u});

  f32x4 oacc[2][4];  // [frag][dtile]
  f32x4 oaccL[2];    // row-sum accumulator (l)
#pragma unroll
  for (int f = 0; f < 2; ++f) {
    oaccL[f] = f32x4{0.f, 0.f, 0.f, 0.f};
#pragma unroll
    for (int d = 0; d < 4; ++d) oacc[f][d] = f32x4{0.f, 0.f, 0.f, 0.f};
  }
  float mrow[2] = {-3e38f, -3e38f};

  const int r8 = tid >> 3;  // staging row 0..31
  const int c8 = tid & 7;   // staging 16B chunk

  auto STAGE = [&](int p, int key0) {
#pragma unroll
    for (int i = 0; i < 2; ++i) {
      int row = i * 32 + r8;
      int sc = (c8 ^ (row & 7)) * 8;  // inverse-swizzled source
      cp16(k + base + (size_t)(key0 + row) * Dc + sc,
           &Ks[p][i * 2048 + wave * 512]);
      cp16(vt + base + (size_t)row * Sc + key0 + sc,
           &Vt[p][i * 2048 + wave * 512]);
    }
  };

  const int sA = (fq ^ (fr & 7)) * 8;
  const int sB = ((fq + 4) ^ (fr & 7)) * 8;

  const int pswz = 2 * (fr & 7);
  const int pr0 = fr * 64 + ((fq * 2) ^ pswz) * 4;
  const int pr1 = fr * 64 + ((fq * 2 + 8) ^ pswz) * 4;

  STAGE(0, 0);
  constexpr int NT = Sc / 64;
  for (int kt = 0; kt < NT; ++kt) {
    const int p = kt & 1;
    if (kt + 1 < NT) {
      STAGE(p ^ 1, (kt + 1) * 64);
      asm volatile("s_waitcnt vmcnt(4)" ::: "memory");
    } else {
      asm volatile("s_waitcnt vmcnt(0)" ::: "memory");
    }
    __builtin_amdgcn_s_barrier();

    bfv8 kf0[4], kf1[4], vf0[4], vf1[4];
#pragma unroll
    for (int t = 0; t < 4; ++t) {
      int e = (t * 16 + fr) * 64;
      kf0[t] = *reinterpret_cast<const bfv8*>(&Ks[p][e + sA]);
      kf1[t] = *reinterpret_cast<const bfv8*>(&Ks[p][e + sB]);
      vf0[t] = *reinterpret_cast<const bfv8*>(&Vt[p][e + sA]);
      vf1[t] = *reinterpret_cast<const bfv8*>(&Vt[p][e + sB]);
    }

#pragma unroll
    for (int f = 0; f < 2; ++f) {
      f32x4 sf[4];
      __builtin_amdgcn_s_setprio(1);
#pragma unroll
      for (int t = 0; t < 4; ++t) {
        sf[t] = f32x4{0.f, 0.f, 0.f, 0.f};
        sf[t] = __builtin_amdgcn_mfma_f32_16x16x32_bf16(kf0[t], qf0[f], sf[t], 0, 0, 0);
        sf[t] = __builtin_amdgcn_mfma_f32_16x16x32_bf16(kf1[t], qf1[f], sf[t], 0, 0, 0);
      }
      __builtin_amdgcn_s_setprio(0);
      float mt0 = fmaxf(fmaxf(sf[0][0], sf[0][1]), fmaxf(sf[0][2], sf[0][3]));
      float mt1 = fmaxf(fmaxf(sf[1][0], sf[1][1]), fmaxf(sf[1][2], sf[1][3]));
      float mt2 = fmaxf(fmaxf(sf[2][0], sf[2][1]), fmaxf(sf[2][2], sf[2][3]));
      float mt3 = fmaxf(fmaxf(sf[3][0], sf[3][1]), fmaxf(sf[3][2], sf[3][3]));
      float pmax = fmaxf(fmaxf(mt0, mt1), fmaxf(mt2, mt3));
      float m = mrow[f];
      float mnew = m;
      if (!__all(pmax <= m + 8.f)) {
        float mt = fmaxf(pmax, __shfl_xor(pmax, 16));
        mt = fmaxf(mt, __shfl_xor(mt, 32));
        mnew = fmaxf(m, mt);
        float alpha = __builtin_amdgcn_exp2f(m - mnew);
        float ar[4];
#pragma unroll
        for (int r = 0; r < 4; ++r) ar[r] = __shfl(alpha, fq * 4 + r);
#pragma unroll
        for (int d = 0; d < 4; ++d)
#pragma unroll
          for (int r = 0; r < 4; ++r) oacc[f][d][r] *= ar[r];
#pragma unroll
        for (int r = 0; r < 4; ++r) oaccL[f][r] *= ar[r];
        mrow[f] = mnew;
      }
      ushort* pw = &Ps[wave][0];
#pragma unroll
      for (int t = 0; t < 4; ++t) {
        uint2 pu;
        pu.x = pkbf(__builtin_amdgcn_exp2f(sf[t][0] - mnew),
                    __builtin_amdgcn_exp2f(sf[t][1] - mnew));
        pu.y = pkbf(__builtin_amdgcn_exp2f(sf[t][2] - mnew),
                    __builtin_amdgcn_exp2f(sf[t][3] - mnew));
        int us = fr * 64 + ((t * 4 + fq) ^ pswz) * 4;
        *reinterpret_cast<uint2*>(&pw[us]) = pu;
      }
      bfv8 pf0 = *reinterpret_cast<const bfv8*>(&pw[pr0]);
      bfv8 pf1 = *reinterpret_cast<const bfv8*>(&pw[pr1]);
      __builtin_amdgcn_s_setprio(1);
#pragma unroll
      for (int d = 0; d < 4; ++d) {
        oacc[f][d] = __builtin_amdgcn_mfma_f32_16x16x32_bf16(pf0, vf0[d], oacc[f][d], 0, 0, 0);
        oacc[f][d] = __builtin_amdgcn_mfma_f32_16x16x32_bf16(pf1, vf1[d], oacc[f][d], 0, 0, 0);
      }
      oaccL[f] = __builtin_amdgcn_mfma_f32_16x16x32_bf16(pf0, ones, oaccL[f], 0, 0, 0);
      oaccL[f] = __builtin_amdgcn_mfma_f32_16x16x32_bf16(pf1, ones, oaccL[f], 0, 0, 0);
      __builtin_amdgcn_s_setprio(0);
    }
    __builtin_amdgcn_sched_barrier(0);
    __builtin_amdgcn_s_barrier();
  }

  const int b = bh >> 4, h = bh & 15;
#pragma unroll
  for (int f = 0; f < 2; ++f) {
    float linv[4];
#pragma unroll
    for (int r = 0; r < 4; ++r) linv[r] = 1.f / oaccL[f][r];
#pragma unroll
    for (int d = 0; d < 4; ++d)
#pragma unroll
      for (int r = 0; r < 4; ++r) {
        int sIdx = q0 + f * 16 + fq * 4 + r;
        o[((size_t)(b * Sc + sIdx)) * Ec + h * 64 + d * 16 + fr] =
            f2bf(oacc[f][d][r] * linv[r]);
      }
  }
}

// -----------------------------------------------------------------------------
extern "C" void kernel_launch(void* const* d_in, const int* in_sizes, int n_in,
                              void* d_out, int out_size, void* d_ws, size_t ws_size,
                              hipStream_t stream) {
  const float* inp = (const float*)d_in[0];
  const float* ln1g = (const float*)d_in[1];
  const float* ln1b = (const float*)d_in[2];
  const float* Wq = (const float*)d_in[3];
  const float* bq = (const float*)d_in[4];
  const float* Wk = (const float*)d_in[5];
  const float* bk = (const float*)d_in[6];
  const float* Wv = (const float*)d_in[7];
  const float* bv = (const float*)d_in[8];
  const float* Wo = (const float*)d_in[9];
  const float* bo = (const float*)d_in[10];
  const float* ln2g = (const float*)d_in[11];
  const float* ln2b = (const float*)d_in[12];
  const float* W1 = (const float*)d_in[13];
  const float* b1 = (const float*)d_in[14];
  const float* W2 = (const float*)d_in[15];
  const float* b2 = (const float*)d_in[16];

  char* wsb = (char*)d_ws;
  size_t off = 0;
  auto alloc = [&](size_t bytes) {
    char* p = wsb + off;
    off += (bytes + 255) & ~(size_t)255;
    return p;
  };
  ushort* xb = (ushort*)alloc((size_t)Mc * Ec * 2);    // x1 = LN1(inp), bf16
  ushort* x2b = (ushort*)alloc((size_t)Mc * Ec * 2);   // x2 = x1 + attnWo, bf16
  ushort* x3b = (ushort*)alloc((size_t)Mc * Ec * 2);   // x3 = LN2(x2), bf16
  ushort* qbuf = (ushort*)alloc((size_t)Mc * Ec * 2);
  ushort* kbuf = (ushort*)alloc((size_t)Mc * Ec * 2);
  ushort* vtbuf = (ushort*)alloc((size_t)Mc * Ec * 2);
  ushort* abuf = (ushort*)alloc((size_t)Mc * Ec * 2);
  ushort* h1 = (ushort*)alloc((size_t)Mc * 2 * Ec * 2);
  ushort* WqkvT = (ushort*)alloc((size_t)3 * Ec * Ec * 2);  // [3E][E]
  ushort* WoT = (ushort*)alloc((size_t)Ec * Ec * 2);
  ushort* W1T = (ushort*)alloc((size_t)Ec * 2 * Ec * 2);
  ushort* W2T = (ushort*)alloc((size_t)Ec * 2 * Ec * 2);
  (void)in_sizes; (void)n_in; (void)out_size; (void)ws_size;

  // all 6 weight converts in one launch (8192 blocks)
  wcvt_all_kernel<<<8192, dim3(32, 8), 0, stream>>>(Wq, Wk, Wv, Wo, W1, W2,
                                                    WqkvT, WoT, W1T, W2T);

  ln_kernel<1><<<Mc, 256, 0, stream>>>(inp, ln1g, ln1b, xb);

  // Fused QKV on the 128² kernel (grid 24x64 = 1536 = 6/CU exact, no tail).
  gemm_kernel<0><<<dim3(3 * Ec / 128, Mc / 128), 256, 0, stream>>>(
      Mc, 3 * Ec, Ec, xb, WqkvT, bq, bk, bv, nullptr, nullptr, qbuf, kbuf,
      vtbuf, 0.18033688f);

  attn_kernel<<<Bc * Hc * (Sc / 128), 256, 0, stream>>>(qbuf, kbuf, vtbuf, abuf);

  // Wo: x2 = attn@Wo + bo + x1 (bf16 resid in, bf16 out)
  gemm_kernel<1><<<dim3(Ec / 128, Mc / 128), 256, 0, stream>>>(
      Mc, Ec, Ec, abuf, WoT, bo, nullptr, nullptr, xb, nullptr, x2b, nullptr,
      nullptr, 1.f);

  ln_kernel<0><<<Mc, 256, 0, stream>>>(x2b, ln2g, ln2b, x3b);

  // W1 + GELU on the 256² 4-phase kernel (grid 8x32 = 256 = exactly 1/CU)
  gemm256_kernel<2><<<dim3(2 * Ec / 256, Mc / 256), 512, 0, stream>>>(
      Mc, 2 * Ec, Ec, x3b, W1T, b1, h1, 1.f);

  // W2: out = h1@W2 + b2 + x3 (bf16 resid, f32 out)
  gemm_kernel<3><<<dim3(Ec / 128, Mc / 128), 256, 0, stream>>>(
      Mc, Ec, 2 * Ec, h1, W2T, b2, nullptr, nullptr, x3b, (float*)d_out,
      nullptr, nullptr, nullptr, 1.f);
}

// Round 18
// 318.884 us; speedup vs baseline: 1.2115x; 1.0459x over previous
//
#include <hip/hip_runtime.h>
#include <hip/hip_bf16.h>

typedef float f32x4 __attribute__((ext_vector_type(4)));
typedef __bf16 bfv8 __attribute__((ext_vector_type(8)));

constexpr int Bc = 4, Sc = 2048, Ec = 1024, Hc = 16, Dc = 64;
constexpr int Mc = Bc * Sc;  // 8192 rows

__device__ __forceinline__ uint pkbf(float lo, float hi) {
  uint r;
  asm("v_cvt_pk_bf16_f32 %0, %1, %2" : "=v"(r) : "v"(lo), "v"(hi));
  return r;
}
__device__ __forceinline__ ushort f2bf(float f) {
  __hip_bfloat16 h = __float2bfloat16(f);
  return __builtin_bit_cast(ushort, h);
}
__device__ __forceinline__ float bf2f(ushort u) {
  return __builtin_bit_cast(float, (uint)u << 16);
}

typedef __attribute__((address_space(1))) unsigned int as1_u32;
typedef __attribute__((address_space(3))) unsigned int as3_u32;
__device__ __forceinline__ void cp16(const ushort* g, ushort* l) {
  // async global->LDS, 16B per lane; LDS dest = wave-uniform base + lane*16
  __builtin_amdgcn_global_load_lds((as1_u32*)g, (as3_u32*)l, 16, 0, 0);
}

// ---------------- all-weights convert+transpose in ONE launch ----------------
__global__ __launch_bounds__(256) void wcvt_all_kernel(
    const float* __restrict__ Wq, const float* __restrict__ Wk,
    const float* __restrict__ Wv, const float* __restrict__ Wo,
    const float* __restrict__ W1, const float* __restrict__ W2,
    ushort* __restrict__ WqkvT, ushort* __restrict__ WoT,
    ushort* __restrict__ W1T, ushort* __restrict__ W2T) {
  int bid = blockIdx.x;
  const float* W;
  ushort* WT;
  int K, N;
  if (bid < 1024) {
    W = Wq; WT = WqkvT; K = 1024; N = 1024;
  } else if (bid < 2048) {
    W = Wk; WT = WqkvT + (size_t)1024 * 1024; K = 1024; N = 1024; bid -= 1024;
  } else if (bid < 3072) {
    W = Wv; WT = WqkvT + (size_t)2 * 1024 * 1024; K = 1024; N = 1024; bid -= 2048;
  } else if (bid < 4096) {
    W = Wo; WT = WoT; K = 1024; N = 1024; bid -= 3072;
  } else if (bid < 6144) {
    W = W1; WT = W1T; K = 1024; N = 2048; bid -= 4096;
  } else {
    W = W2; WT = W2T; K = 2048; N = 1024; bid -= 6144;
  }
  const int nbx = K / 32;
  const int k0 = (bid % nbx) * 32, n0 = (bid / nbx) * 32;
  __shared__ float t[32][33];
  int tx = threadIdx.x, ty = threadIdx.y;  // (32,8)
#pragma unroll
  for (int i = 0; i < 32; i += 8)
    t[ty + i][tx] = W[(size_t)(k0 + ty + i) * N + n0 + tx];
  __syncthreads();
#pragma unroll
  for (int i = 0; i < 32; i += 8)
    WT[(size_t)(n0 + ty + i) * K + k0 + tx] = f2bf(t[tx][ty + i]);
}

// ---------------- LayerNorm: row of 1024, one block per row ------------------
// INF32=1: f32 input; INF32=0: bf16 input. Output bf16 only.
template <int INF32>
__global__ __launch_bounds__(256) void ln_kernel(const void* in,
                                                 const float* __restrict__ g,
                                                 const float* __restrict__ bb,
                                                 ushort* ob) {
  int row = blockIdx.x;
  int t = threadIdx.x;
  float4 x;
  if constexpr (INF32) {
    x = reinterpret_cast<const float4*>((const float*)in + (size_t)row * Ec)[t];
  } else {
    uint2 u = reinterpret_cast<const uint2*>((const ushort*)in + (size_t)row * Ec)[t];
    x.x = __builtin_bit_cast(float, u.x << 16);
    x.y = __builtin_bit_cast(float, u.x & 0xFFFF0000u);
    x.z = __builtin_bit_cast(float, u.y << 16);
    x.w = __builtin_bit_cast(float, u.y & 0xFFFF0000u);
  }
  float s = x.x + x.y + x.z + x.w;
  float q = x.x * x.x + x.y * x.y + x.z * x.z + x.w * x.w;
#pragma unroll
  for (int o = 32; o > 0; o >>= 1) {
    s += __shfl_down(s, o);
    q += __shfl_down(q, o);
  }
  __shared__ float red[10];
  int wv = t >> 6;
  if ((t & 63) == 0) { red[wv] = s; red[4 + wv] = q; }
  __syncthreads();
  if (t == 0) {
    float S = red[0] + red[1] + red[2] + red[3];
    float Q = red[4] + red[5] + red[6] + red[7];
    float mu = S * (1.f / Ec);
    float var = Q * (1.f / Ec) - mu * mu;
    red[8] = mu;
    red[9] = rsqrtf(var + 1e-5f);
  }
  __syncthreads();
  float mu = red[8], rs = red[9];
  float4 gg = reinterpret_cast<const float4*>(g)[t];
  float4 b4 = reinterpret_cast<const float4*>(bb)[t];
  float4 y;
  y.x = (x.x - mu) * rs * gg.x + b4.x;
  y.y = (x.y - mu) * rs * gg.y + b4.y;
  y.z = (x.z - mu) * rs * gg.z + b4.z;
  y.w = (x.w - mu) * rs * gg.w + b4.w;
  uint2 u;
  u.x = pkbf(y.x, y.y);
  u.y = pkbf(y.z, y.w);
  reinterpret_cast<uint2*>(ob + (size_t)row * Ec)[t] = u;
}

// ---------------- GEMM 128x128: BK=64, LDS dbuf, counted vmcnt(8) ------------
// MODE 0: fused QKV; MODE 1: bf16 acc+bias+bf16resid; MODE 3: f32 out
template <int MODE>
__global__ __launch_bounds__(256, 2) void gemm_kernel(
    int M, int N, int K, const ushort* __restrict__ A,
    const ushort* __restrict__ BT, const float* __restrict__ b0,
    const float* __restrict__ b1, const float* __restrict__ b2,
    const ushort* __restrict__ rb, float* outF, ushort* o0, ushort* o1,
    ushort* o2, float qscale) {
  __shared__ __align__(16) ushort As[2][128 * 64];
  __shared__ __align__(16) ushort Bs[2][128 * 64];
  const int tid = threadIdx.x;
  const int lane = tid & 63, wave = tid >> 6;
  const int wr = wave >> 1, wc = wave & 1;
  const int fr = lane & 15, fq = lane >> 4;
  const int nx = gridDim.x;
  int flat = blockIdx.x + nx * blockIdx.y;
  int cpx = (nx * gridDim.y) >> 3;
  int work = (flat & 7) * cpx + (flat >> 3);
  const int n0 = (work % nx) * 128, m0 = (work / nx) * 128;

  f32x4 acc[4][4];
#pragma unroll
  for (int i = 0; i < 4; i++)
#pragma unroll
    for (int j = 0; j < 4; j++) acc[i][j] = f32x4{0.f, 0.f, 0.f, 0.f};

  const int srow = tid >> 3;   // 0..31 (+32 per chunk)
  const int sslot = tid & 7;   // 16B slot within 128B row

  auto STAGE = [&](int p, int k0) {
#pragma unroll
    for (int c = 0; c < 4; ++c) {
      int row = c * 32 + srow;
      int scol = (sslot ^ (row & 7)) * 8;  // inverse-swizzled source (3-bit)
      cp16(A + (size_t)(m0 + row) * K + k0 + scol,
           &As[p][(c * 256 + wave * 64) * 8]);
      cp16(BT + (size_t)(n0 + row) * K + k0 + scol,
           &Bs[p][(c * 256 + wave * 64) * 8]);
    }
  };

  STAGE(0, 0);
  const int nt = K >> 6;
  for (int kt = 0; kt < nt; ++kt) {
    const int p = kt & 1;
    if (kt + 1 < nt) {
      STAGE(p ^ 1, (kt + 1) << 6);
      asm volatile("s_waitcnt vmcnt(8)" ::: "memory");  // tile kt landed
    } else {
      asm volatile("s_waitcnt vmcnt(0)" ::: "memory");
    }
    __builtin_amdgcn_s_barrier();
#pragma unroll
    for (int kk = 0; kk < 2; ++kk) {
      bfv8 af[4], bf[4];
#pragma unroll
      for (int m = 0; m < 4; m++) {
        int row = wr * 64 + m * 16 + fr;
        af[m] = *reinterpret_cast<const bfv8*>(
            &As[p][row * 64 + (((kk * 4 + fq) ^ (fr & 7)) * 8)]);
      }
#pragma unroll
      for (int n = 0; n < 4; n++) {
        int row = wc * 64 + n * 16 + fr;
        bf[n] = *reinterpret_cast<const bfv8*>(
            &Bs[p][row * 64 + (((kk * 4 + fq) ^ (fr & 7)) * 8)]);
      }
      __builtin_amdgcn_s_setprio(1);
#pragma unroll
      for (int m = 0; m < 4; m++)
#pragma unroll
        for (int n = 0; n < 4; n++)
          acc[m][n] =
              __builtin_amdgcn_mfma_f32_16x16x32_bf16(af[m], bf[n], acc[m][n], 0, 0, 0);
      __builtin_amdgcn_s_setprio(0);
    }
    __builtin_amdgcn_sched_barrier(0);
    __builtin_amdgcn_s_barrier();
  }

#pragma unroll
  for (int m = 0; m < 4; m++) {
#pragma unroll
    for (int n = 0; n < 4; n++) {
      const int row0 = m0 + wr * 64 + m * 16 + fq * 4;
      const int col = n0 + wc * 64 + n * 16 + fr;
      if constexpr (MODE == 0) {
        const int region = col >> 10, c1 = col & (Ec - 1);
        const int b = row0 >> 11, s0 = row0 & (Sc - 1);
        const int h = c1 >> 6, d = c1 & (Dc - 1);
        const float bb = (region == 0 ? b0 : region == 1 ? b1 : b2)[c1];
        if (region == 2) {
          uint2 u;
          u.x = pkbf(acc[m][n][0] + bb, acc[m][n][1] + bb);
          u.y = pkbf(acc[m][n][2] + bb, acc[m][n][3] + bb);
          *reinterpret_cast<uint2*>(
              &o2[(((size_t)b * Hc + h) * Dc + d) * Sc + s0]) = u;
        } else {
          ushort* dst = region ? o1 : o0;
          const float sc = region ? 1.f : qscale;
#pragma unroll
          for (int r = 0; r < 4; r++)
            dst[(((size_t)b * Hc + h) * Sc + s0 + r) * Dc + d] =
                f2bf((acc[m][n][r] + bb) * sc);
        }
      } else {
        const float bb = b0[col];
#pragma unroll
        for (int r = 0; r < 4; r++) {
          int row = row0 + r;
          size_t idx = (size_t)row * N + col;
          float vacc = acc[m][n][r] + bb + bf2f(rb[idx]);
          if constexpr (MODE == 1) {
            o0[idx] = f2bf(vacc);
          } else {
            outF[idx] = vacc;
          }
        }
      }
    }
  }
}

// ======== 256x256 8-wave 4-phase GEMM (W1 only: grid 256 = exactly 1/CU) ====
// MODE 2: bf16 gelu(acc+bias)
template <int MODE>
__global__ __launch_bounds__(512, 2) void gemm256_kernel(
    int M, int N, int K, const ushort* __restrict__ A,
    const ushort* __restrict__ BT, const float* __restrict__ b0,
    ushort* o0, float qscale) {
  __shared__ __align__(16) ushort As[2][256 * 64];
  __shared__ __align__(16) ushort Bs[2][256 * 64];
  const int tid = threadIdx.x;
  const int lane = tid & 63, wave = tid >> 6;  // 8 waves
  const int wr = wave >> 2, wc = wave & 3;     // 2 x 4
  const int fr = lane & 15, fq = lane >> 4;
  const int nx = gridDim.x;
  int flat = blockIdx.x + nx * blockIdx.y;
  int cpx = (nx * gridDim.y) >> 3;
  int work = (flat & 7) * cpx + (flat >> 3);
  const int n0 = (work % nx) * 256, m0 = (work / nx) * 256;

  f32x4 acc[8][4];
#pragma unroll
  for (int i = 0; i < 8; i++)
#pragma unroll
    for (int j = 0; j < 4; j++) acc[i][j] = f32x4{0.f, 0.f, 0.f, 0.f};

  const int srow = tid >> 3;  // 0..63
  const int sslot = tid & 7;

  auto STAGE = [&](int p, int k0) {
#pragma unroll
    for (int c = 0; c < 4; ++c) {
      int row = c * 64 + srow;
      int scol = (sslot ^ (row & 7)) * 8;  // inverse-swizzled source
      cp16(A + (size_t)(m0 + row) * K + k0 + scol,
           &As[p][(c * 64 + wave * 8) * 64]);
      cp16(BT + (size_t)(n0 + row) * K + k0 + scol,
           &Bs[p][(c * 64 + wave * 8) * 64]);
    }
  };

  STAGE(0, 0);
  const int nt = K >> 6;
  for (int kt = 0; kt < nt; ++kt) {
    const int p = kt & 1;
    if (kt + 1 < nt) {
      STAGE(p ^ 1, (kt + 1) << 6);
      asm volatile("s_waitcnt vmcnt(8)" ::: "memory");  // tile kt landed
    } else {
      asm volatile("s_waitcnt vmcnt(0)" ::: "memory");
    }
    __builtin_amdgcn_s_barrier();
#pragma unroll
    for (int kk = 0; kk < 2; ++kk) {
      bfv8 bfr[4];
#pragma unroll
      for (int n = 0; n < 4; ++n) {
        int row = wc * 64 + n * 16 + fr;
        bfr[n] = *reinterpret_cast<const bfv8*>(
            &Bs[p][row * 64 + (((kk * 4 + fq) ^ (row & 7)) * 8)]);
      }
#pragma unroll
      for (int mh = 0; mh < 2; ++mh) {
        bfv8 af[4];
#pragma unroll
        for (int mm = 0; mm < 4; ++mm) {
          int row = wr * 128 + (mh * 4 + mm) * 16 + fr;
          af[mm] = *reinterpret_cast<const bfv8*>(
              &As[p][row * 64 + (((kk * 4 + fq) ^ (row & 7)) * 8)]);
        }
        __builtin_amdgcn_s_setprio(1);
#pragma unroll
        for (int mm = 0; mm < 4; ++mm)
#pragma unroll
          for (int n = 0; n < 4; ++n)
            acc[mh * 4 + mm][n] = __builtin_amdgcn_mfma_f32_16x16x32_bf16(
                af[mm], bfr[n], acc[mh * 4 + mm][n], 0, 0, 0);
        __builtin_amdgcn_s_setprio(0);
        if (!(kk == 1 && mh == 1)) __builtin_amdgcn_s_barrier();  // phase edge
      }
    }
    __builtin_amdgcn_sched_barrier(0);
    __builtin_amdgcn_s_barrier();  // tile edge: all reads of buf p done
  }

#pragma unroll
  for (int m = 0; m < 8; m++) {
#pragma unroll
    for (int n = 0; n < 4; n++) {
      const int row0 = m0 + wr * 128 + m * 16 + fq * 4;
      const int col = n0 + wc * 64 + n * 16 + fr;
      const float bb = b0[col];
#pragma unroll
      for (int r = 0; r < 4; r++) {
        float vacc = acc[m][n][r] + bb;
        vacc = 0.5f * vacc * (1.f + erff(vacc * 0.70710678118f));
        o0[(size_t)(row0 + r) * N + col] = f2bf(vacc);
      }
    }
  }
}

// ---------------- Flash attention: 8 waves x 16 q-rows, 128 rows/block -------
// Same proven counted-vmcnt K/V double-buffer + l-sum-via-ones-MFMA +
// swizzled Ps as R13/R17, but ONE q-frag per wave (serial chain halved) and
// 8 waves/block (512 thr). Staging = exactly 1 cp16/thread for K and V
// (wave-contiguous dst verified); 2 loads/thread/tile -> vmcnt(2).
// LDS = 2*8K(K) + 2*8K(V) + 16K(Ps) = 48 KB -> 3 blocks/CU.
__global__ __launch_bounds__(512) void attn_kernel(const ushort* __restrict__ q,
                                                   const ushort* __restrict__ k,
                                                   const ushort* __restrict__ vt,
                                                   ushort* __restrict__ o) {
  int flat = blockIdx.x;                     // 1024 blocks
  int swz = (flat & 7) * 128 + (flat >> 3);  // XCD-chunked: 8 heads per XCD
  const int qb = swz & 15;                   // 16 q-blocks of 128 rows
  const int bh = swz >> 4;
  const int tid = threadIdx.x, lane = tid & 63, wave = tid >> 6;  // 8 waves
  const int fr = lane & 15, fq = lane >> 4;
  const size_t base = (size_t)bh * Sc * Dc;
  const int q0 = qb * 128 + wave * 16;

  __shared__ __align__(16) ushort Ks[2][64 * 64];  // [key][d], XOR-swizzled
  __shared__ __align__(16) ushort Vt[2][64 * 64];  // [d][key], XOR-swizzled
  __shared__ __align__(16) ushort Ps[8][16 * 64];  // per-wave P, XOR-swizzled

  bfv8 qf0, qf1;
  {
    const ushort* qp = q + base + (size_t)(q0 + fr) * Dc + fq * 8;
    qf0 = *reinterpret_cast<const bfv8*>(qp);
    qf1 = *reinterpret_cast<const bfv8*>(qp + 32);
  }

  const bfv8 ones = __builtin_bit_cast(bfv8, uint4{0x3F803F80u, 0x3F803F80u,
                                                  0x3F803F80u, 0x3F803F80u});

  f32x4 oacc[4];  // [dtile]
  f32x4 oaccL;    // row-sum accumulator (l)
  oaccL = f32x4{0.f, 0.f, 0.f, 0.f};
#pragma unroll
  for (int d = 0; d < 4; ++d) oacc[d] = f32x4{0.f, 0.f, 0.f, 0.f};
  float mrow = -3e38f;

  const int r8 = tid >> 3;  // staging row 0..63
  const int c8 = tid & 7;   // staging 16B chunk

  auto STAGE = [&](int p, int key0) {
    int sc = (c8 ^ (r8 & 7)) * 8;  // inverse-swizzled source
    cp16(k + base + (size_t)(key0 + r8) * Dc + sc, &Ks[p][wave * 512]);
    cp16(vt + base + (size_t)r8 * Sc + key0 + sc, &Vt[p][wave * 512]);
  };

  const int sA = (fq ^ (fr & 7)) * 8;
  const int sB = ((fq + 4) ^ (fr & 7)) * 8;

  const int pswz = 2 * (fr & 7);
  const int pr0 = fr * 64 + ((fq * 2) ^ pswz) * 4;
  const int pr1 = fr * 64 + ((fq * 2 + 8) ^ pswz) * 4;

  STAGE(0, 0);
  constexpr int NT = Sc / 64;
  for (int kt = 0; kt < NT; ++kt) {
    const int p = kt & 1;
    if (kt + 1 < NT) {
      STAGE(p ^ 1, (kt + 1) * 64);  // 2 loads for tile kt+1 stay in flight
      asm volatile("s_waitcnt vmcnt(2)" ::: "memory");  // tile kt landed
    } else {
      asm volatile("s_waitcnt vmcnt(0)" ::: "memory");
    }
    __builtin_amdgcn_s_barrier();

    bfv8 kf0[4], kf1[4], vf0[4], vf1[4];
#pragma unroll
    for (int t = 0; t < 4; ++t) {
      int e = (t * 16 + fr) * 64;
      kf0[t] = *reinterpret_cast<const bfv8*>(&Ks[p][e + sA]);
      kf1[t] = *reinterpret_cast<const bfv8*>(&Ks[p][e + sB]);
      vf0[t] = *reinterpret_cast<const bfv8*>(&Vt[p][e + sA]);
      vf1[t] = *reinterpret_cast<const bfv8*>(&Vt[p][e + sB]);
    }

    f32x4 sf[4];
    __builtin_amdgcn_s_setprio(1);
#pragma unroll
    for (int t = 0; t < 4; ++t) {
      sf[t] = f32x4{0.f, 0.f, 0.f, 0.f};
      sf[t] = __builtin_amdgcn_mfma_f32_16x16x32_bf16(kf0[t], qf0, sf[t], 0, 0, 0);
      sf[t] = __builtin_amdgcn_mfma_f32_16x16x32_bf16(kf1[t], qf1, sf[t], 0, 0, 0);
    }
    __builtin_amdgcn_s_setprio(0);
    // lane holds S[q=fr][key = t*16 + fq*4 + r], log2 domain
    float mt0 = fmaxf(fmaxf(sf[0][0], sf[0][1]), fmaxf(sf[0][2], sf[0][3]));
    float mt1 = fmaxf(fmaxf(sf[1][0], sf[1][1]), fmaxf(sf[1][2], sf[1][3]));
    float mt2 = fmaxf(fmaxf(sf[2][0], sf[2][1]), fmaxf(sf[2][2], sf[2][3]));
    float mt3 = fmaxf(fmaxf(sf[3][0], sf[3][1]), fmaxf(sf[3][2], sf[3][3]));
    float pmax = fmaxf(fmaxf(mt0, mt1), fmaxf(mt2, mt3));
    float mnew = mrow;
    if (!__all(pmax <= mrow + 8.f)) {
      float mt = fmaxf(pmax, __shfl_xor(pmax, 16));
      mt = fmaxf(mt, __shfl_xor(mt, 32));
      mnew = fmaxf(mrow, mt);
      float alpha = __builtin_amdgcn_exp2f(mrow - mnew);
      float ar[4];
#pragma unroll
      for (int r = 0; r < 4; ++r) ar[r] = __shfl(alpha, fq * 4 + r);
#pragma unroll
      for (int d = 0; d < 4; ++d)
#pragma unroll
        for (int r = 0; r < 4; ++r) oacc[d][r] *= ar[r];
#pragma unroll
      for (int r = 0; r < 4; ++r) oaccL[r] *= ar[r];
      mrow = mnew;
    }
    ushort* pw = &Ps[wave][0];
#pragma unroll
    for (int t = 0; t < 4; ++t) {
      uint2 pu;
      pu.x = pkbf(__builtin_amdgcn_exp2f(sf[t][0] - mnew),
                  __builtin_amdgcn_exp2f(sf[t][1] - mnew));
      pu.y = pkbf(__builtin_amdgcn_exp2f(sf[t][2] - mnew),
                  __builtin_amdgcn_exp2f(sf[t][3] - mnew));
      int us = fr * 64 + ((t * 4 + fq) ^ pswz) * 4;
      *reinterpret_cast<uint2*>(&pw[us]) = pu;
    }
    bfv8 pf0 = *reinterpret_cast<const bfv8*>(&pw[pr0]);
    bfv8 pf1 = *reinterpret_cast<const bfv8*>(&pw[pr1]);
    __builtin_amdgcn_s_setprio(1);
#pragma unroll
    for (int d = 0; d < 4; ++d) {
      oacc[d] = __builtin_amdgcn_mfma_f32_16x16x32_bf16(pf0, vf0[d], oacc[d], 0, 0, 0);
      oacc[d] = __builtin_amdgcn_mfma_f32_16x16x32_bf16(pf1, vf1[d], oacc[d], 0, 0, 0);
    }
    oaccL = __builtin_amdgcn_mfma_f32_16x16x32_bf16(pf0, ones, oaccL, 0, 0, 0);
    oaccL = __builtin_amdgcn_mfma_f32_16x16x32_bf16(pf1, ones, oaccL, 0, 0, 0);
    __builtin_amdgcn_s_setprio(0);

    __builtin_amdgcn_sched_barrier(0);
    __builtin_amdgcn_s_barrier();
  }

  const int b = bh >> 4, h = bh & 15;
  float linv[4];
#pragma unroll
  for (int r = 0; r < 4; ++r) linv[r] = 1.f / oaccL[r];
#pragma unroll
  for (int d = 0; d < 4; ++d)
#pragma unroll
    for (int r = 0; r < 4; ++r) {
      int sIdx = q0 + fq * 4 + r;
      o[((size_t)(b * Sc + sIdx)) * Ec + h * 64 + d * 16 + fr] =
          f2bf(oacc[d][r] * linv[r]);
    }
}

// -----------------------------------------------------------------------------
extern "C" void kernel_launch(void* const* d_in, const int* in_sizes, int n_in,
                              void* d_out, int out_size, void* d_ws, size_t ws_size,
                              hipStream_t stream) {
  const float* inp = (const float*)d_in[0];
  const float* ln1g = (const float*)d_in[1];
  const float* ln1b = (const float*)d_in[2];
  const float* Wq = (const float*)d_in[3];
  const float* bq = (const float*)d_in[4];
  const float* Wk = (const float*)d_in[5];
  const float* bk = (const float*)d_in[6];
  const float* Wv = (const float*)d_in[7];
  const float* bv = (const float*)d_in[8];
  const float* Wo = (const float*)d_in[9];
  const float* bo = (const float*)d_in[10];
  const float* ln2g = (const float*)d_in[11];
  const float* ln2b = (const float*)d_in[12];
  const float* W1 = (const float*)d_in[13];
  const float* b1 = (const float*)d_in[14];
  const float* W2 = (const float*)d_in[15];
  const float* b2 = (const float*)d_in[16];

  char* wsb = (char*)d_ws;
  size_t off = 0;
  auto alloc = [&](size_t bytes) {
    char* p = wsb + off;
    off += (bytes + 255) & ~(size_t)255;
    return p;
  };
  ushort* xb = (ushort*)alloc((size_t)Mc * Ec * 2);    // x1 = LN1(inp), bf16
  ushort* x2b = (ushort*)alloc((size_t)Mc * Ec * 2);   // x2 = x1 + attnWo, bf16
  ushort* x3b = (ushort*)alloc((size_t)Mc * Ec * 2);   // x3 = LN2(x2), bf16
  ushort* qbuf = (ushort*)alloc((size_t)Mc * Ec * 2);
  ushort* kbuf = (ushort*)alloc((size_t)Mc * Ec * 2);
  ushort* vtbuf = (ushort*)alloc((size_t)Mc * Ec * 2);
  ushort* abuf = (ushort*)alloc((size_t)Mc * Ec * 2);
  ushort* h1 = (ushort*)alloc((size_t)Mc * 2 * Ec * 2);
  ushort* WqkvT = (ushort*)alloc((size_t)3 * Ec * Ec * 2);  // [3E][E]
  ushort* WoT = (ushort*)alloc((size_t)Ec * Ec * 2);
  ushort* W1T = (ushort*)alloc((size_t)Ec * 2 * Ec * 2);
  ushort* W2T = (ushort*)alloc((size_t)Ec * 2 * Ec * 2);
  (void)in_sizes; (void)n_in; (void)out_size; (void)ws_size;

  // all 6 weight converts in one launch (8192 blocks)
  wcvt_all_kernel<<<8192, dim3(32, 8), 0, stream>>>(Wq, Wk, Wv, Wo, W1, W2,
                                                    WqkvT, WoT, W1T, W2T);

  ln_kernel<1><<<Mc, 256, 0, stream>>>(inp, ln1g, ln1b, xb);

  // Fused QKV on the 128² kernel (grid 24x64 = 1536 = 6/CU exact, no tail).
  gemm_kernel<0><<<dim3(3 * Ec / 128, Mc / 128), 256, 0, stream>>>(
      Mc, 3 * Ec, Ec, xb, WqkvT, bq, bk, bv, nullptr, nullptr, qbuf, kbuf,
      vtbuf, 0.18033688f);

  attn_kernel<<<Bc * Hc * (Sc / 128), 512, 0, stream>>>(qbuf, kbuf, vtbuf, abuf);

  // Wo: x2 = attn@Wo + bo + x1 (bf16 resid in, bf16 out)
  gemm_kernel<1><<<dim3(Ec / 128, Mc / 128), 256, 0, stream>>>(
      Mc, Ec, Ec, abuf, WoT, bo, nullptr, nullptr, xb, nullptr, x2b, nullptr,
      nullptr, 1.f);

  ln_kernel<0><<<Mc, 256, 0, stream>>>(x2b, ln2g, ln2b, x3b);

  // W1 + GELU on the 256² 4-phase kernel (grid 8x32 = 256 = exactly 1/CU)
  gemm256_kernel<2><<<dim3(2 * Ec / 256, Mc / 256), 512, 0, stream>>>(
      Mc, 2 * Ec, Ec, x3b, W1T, b1, h1, 1.f);

  // W2: out = h1@W2 + b2 + x3 (bf16 resid, f32 out)
  gemm_kernel<3><<<dim3(Ec / 128, Mc / 128), 256, 0, stream>>>(
      Mc, Ec, 2 * Ec, h1, W2T, b2, nullptr, nullptr, x3b, (float*)d_out,
      nullptr, nullptr, nullptr, 1.f);
}